// Round 15
// baseline (1119.241 us; speedup 1.0000x reference)
//
#include <hip/hip_runtime.h>
#include <stdint.h>
#include <math.h>

// ---------------------------------------------------------------------------
// MRF codebook generator: bit-exact reproduction of the JAX reference.
// Round 28: 10 sampler waves x 2 candidates + 6 gen waves (16 waves total).
//  - R27 (champion 836 us): gen cost is VALU pipe OCCUPANCY (f64 libm logs,
//    ~2250 cy/SIMD/step) which adds ~linearly to the sampler chain; it
//    cannot hide at instruction granularity. Penalty scales with sampler
//    chain length -> shorten the chain: candidate loops 4-way -> 10-way
//    (un/exp/z ~2100 -> ~850 cy) and the contention window shrinks.
//  - Mapping ig = 2*wid + i (order-preserving); rmax exact any order;
//    lsum f64 association change only (same validated class as R23/R26/27);
//    argmax explicit (z, lowest-k) total order -> partition invariant.
//  - Gen: 6 waves, 384 lanes; segments cover [0,384)+[1152,1280) /
//    [384,768) / [768,1152) — every k exactly once, same gumbel_at/keys/j.
//  - Everything else structurally identical to R27 (absmax 0.0 lineage).
// Fallback: legacy mode-0 kernel kept.
// ---------------------------------------------------------------------------

#define JAX_PARTITIONABLE 1

#define T_COLS 256
#define B_ROWS 128
#define KC     1280
#define PTOP   1024
#define RRAND  256
#define WWIN   32
#define NCAND  20            // KC / 64
#define NSW    10            // sampler waves per block
#define NGEN   6             // gen waves per block
#define NTHR   ((NSW + NGEN) * 64)   // 1024
#define NCPW   2             // candidates per lane per sampler wave
#define BLOCK_S 1024         // legacy fallback block
#define NWAVE_S (BLOCK_S / 64)

__device__ __constant__ int dC[17][17] = {
  {1},
  {1,1},
  {1,2,1},
  {1,3,3,1},
  {1,4,6,4,1},
  {1,5,10,10,5,1},
  {1,6,15,20,15,6,1},
  {1,7,21,35,35,21,7,1},
  {1,8,28,56,70,56,28,8,1},
  {1,9,36,84,126,126,84,36,9,1},
  {1,10,45,120,210,252,210,120,45,10,1},
  {1,11,55,165,330,462,462,330,165,55,11,1},
  {1,12,66,220,495,792,924,792,495,220,66,12,1},
  {1,13,78,286,715,1287,1716,1716,1287,715,286,78,13,1},
  {1,14,91,364,1001,2002,3003,3432,3003,2002,1001,364,91,14,1},
  {1,15,105,455,1365,3003,5005,6435,6435,5005,3003,1365,455,105,15,1},
  {1,16,120,560,1820,4368,8008,11440,12870,11440,8008,4368,1820,560,120,16,1}
};

// Threefry-2x32, 20 rounds, JAX key schedule.
__device__ __forceinline__ void tf_block(uint32_t k0, uint32_t k1,
                                         uint32_t x0, uint32_t x1,
                                         uint32_t& o0, uint32_t& o1) {
  uint32_t ks2 = k0 ^ k1 ^ 0x1BD11BDAu;
  x0 += k0; x1 += k1;
#define TFR(r) { x0 += x1; x1 = (x1 << (r)) | (x1 >> (32 - (r))); x1 ^= x0; }
  TFR(13) TFR(15) TFR(26) TFR(6)   x0 += k1;  x1 += ks2 + 1u;
  TFR(17) TFR(29) TFR(16) TFR(24)  x0 += ks2; x1 += k0 + 2u;
  TFR(13) TFR(15) TFR(26) TFR(6)   x0 += k0;  x1 += k1 + 3u;
  TFR(17) TFR(29) TFR(16) TFR(24)  x0 += k1;  x1 += ks2 + 4u;
  TFR(13) TFR(15) TFR(26) TFR(6)   x0 += ks2; x1 += k0 + 5u;
#undef TFR
  o0 = x0; o1 = x1;
}

// fold_in(key(42), step) -> k_rand/k_samp/randint-k2 per PRNG mode.
__device__ __forceinline__ void derive_keys(int step,
                                            uint32_t* krand, uint32_t* ksamp,
                                            uint32_t* k2) {
  uint32_t y0, y1;
  tf_block(0u, 42u, 0u, (uint32_t)step, y0, y1);
  uint32_t kr0 = y0, kr1 = y1;
#if JAX_PARTITIONABLE
  uint32_t r0, r1;
  tf_block(kr0, kr1, 0u, 0u, r0, r1);            // k_rand
  if (krand) { krand[0] = r0; krand[1] = r1; }
  if (ksamp) { tf_block(kr0, kr1, 0u, 1u, y0, y1); ksamp[0] = y0; ksamp[1] = y1; }
  if (k2)    { tf_block(r0, r1, 0u, 1u, y0, y1);  k2[0] = y0;  k2[1] = y1; }
#else
  uint32_t a0,a1,b0,b1;
  tf_block(kr0, kr1, 0u, 2u, a0, a1);
  tf_block(kr0, kr1, 1u, 3u, b0, b1);
  if (krand) { krand[0] = a0; krand[1] = b0; }
  if (ksamp) { ksamp[0] = a1; ksamp[1] = b1; }
  if (k2) {
    uint32_t c0,c1,d0,d1;
    tf_block(a0, b0, 0u, 2u, c0, c1);
    tf_block(a0, b0, 1u, 3u, d0, d1);
    k2[0] = c1; k2[1] = d1;
  }
#endif
}

// JAX uniform(tiny,1) -> gumbel, fp32 logs correctly-rounded-from-double.
__device__ __forceinline__ float gumbel_from_bits(uint32_t bits) {
  uint32_t fb = (bits >> 9) | 0x3f800000u;
  float f = __uint_as_float(fb) - 1.0f;
  float u = (f == 0.0f) ? 1.17549435e-38f : f;
  float l1 = (float)log((double)u);
  float l2 = (float)log((double)(-l1));
  return -l2;
}

__device__ __forceinline__ float gumbel_at(uint32_t ks0, uint32_t ks1, uint32_t j) {
  uint32_t g0, g1;
#if JAX_PARTITIONABLE
  tf_block(ks0, ks1, 0u, j, g0, g1);
  return gumbel_from_bits(g0 ^ g1);
#else
  uint32_t half = (uint32_t)(B_ROWS * KC / 2);
  if (j < half) { tf_block(ks0, ks1, j, j + half, g0, g1);  return gumbel_from_bits(g0); }
  else          { tf_block(ks0, ks1, j - half, j, g0, g1);  return gumbel_from_bits(g1); }
#endif
}

// ---------------- precompute kernel C: cand[step][k] ------------------------
__global__ void __launch_bounds__(256)
cand_kernel(unsigned short* __restrict__ candg) {
  const int step = blockIdx.x;
  const int tid  = threadIdx.x;
  __shared__ int s_dC[17][17];
  __shared__ int s_gw0[17], s_gw1[17], s_gbase[17];
  __shared__ int s_ngrp;
  __shared__ uint32_t s_k2[2];
  for (int i = tid; i < 289; i += 256) s_dC[i/17][i%17] = dC[i/17][i%17];
  if (tid == 0) {
    uint32_t k2[2];
    derive_keys(step, nullptr, nullptr, k2);
    s_k2[0] = k2[0]; s_k2[1] = k2[1];
    int ws[17], am[17];
    for (int w = 0; w < 17; ++w) {
      int m = 16 * w - 256 + step;
      am[w] = m < 0 ? -m : m;
      ws[w] = w;
    }
    for (int a2 = 1; a2 < 17; ++a2) {
      int wv = ws[a2], kv = am[wv];
      int j2 = a2 - 1;
      while (j2 >= 0 && am[ws[j2]] > kv) { ws[j2 + 1] = ws[j2]; --j2; }
      ws[j2 + 1] = wv;
    }
    int ng = 0, base = 0, idx = 0;
    while (idx < 17) {
      int w0 = ws[idx]; int a0v = am[w0]; int w1 = -1;
      if (idx + 1 < 17 && am[ws[idx + 1]] == a0v) { w1 = ws[idx + 1]; ++idx; }
      ++idx;
      s_gw0[ng] = w0; s_gw1[ng] = w1; s_gbase[ng] = base;
      base += dC[16][w0] + (w1 >= 0 ? dC[16][w1] : 0);
      ++ng;
      if (base >= PTOP) break;
    }
    s_ngrp = ng;
  }
  __syncthreads();
  for (int p = tid; p < PTOP; p += 256) {
    int g = 0;
    for (int t2 = 1; t2 < s_ngrp; ++t2) if (s_gbase[t2] <= p) g = t2;
    int q  = p - s_gbase[g];
    int r0 = s_gw0[g], r1 = s_gw1[g];
    uint32_t code = 0;
    for (int pos = 15; pos >= 0; --pos) {
      int n0 = ((r0 >= 0 && r0 <= pos) ? s_dC[pos][r0] : 0)
             + ((r1 >= 0 && r1 <= pos) ? s_dC[pos][r1] : 0);
      if (q >= n0) { q -= n0; code |= (1u << pos); --r0; if (r1 >= 0) --r1; }
    }
    candg[step * KC + p] = (unsigned short)code;
  }
  {
    int t2 = tid;
    uint32_t a0, a1;
#if JAX_PARTITIONABLE
    tf_block(s_k2[0], s_k2[1], 0u, (uint32_t)t2, a0, a1);
    candg[step * KC + PTOP + t2] = (unsigned short)((a0 ^ a1) & 0xFFFFu);
#else
    if (t2 < 128) { tf_block(s_k2[0], s_k2[1], (uint32_t)t2, (uint32_t)(128 + t2), a0, a1);
                    candg[step * KC + PTOP + t2] = (unsigned short)(a0 & 0xFFFFu); }
    else          { tf_block(s_k2[0], s_k2[1], (uint32_t)(t2 - 128), (uint32_t)t2, a0, a1);
                    candg[step * KC + PTOP + t2] = (unsigned short)(a1 & 0xFFFFu); }
#endif
  }
}

// ---------------- VALU-pipe cross-lane primitives ---------------------------
// offset 32: v_permlane32_swap_b32 with both operands = x -> vsrc result is
// [x.hi32, x.hi32]: lanes 0-31 receive lane i+32.
__device__ __forceinline__ unsigned pl_down32_u(unsigned x) {
  unsigned d = x, s = x;
  asm volatile("s_nop 1\n\tv_permlane32_swap_b32 %0, %1" : "+v"(d), "+v"(s));
  return s;
}
// offset 16: v_permlane16_swap_b32 -> lanes 0-15 get lane i+16.
__device__ __forceinline__ unsigned pl_down16_u(unsigned x) {
  unsigned d = x, s = x;
  asm volatile("s_nop 1\n\tv_permlane16_swap_b32 %0, %1" : "+v"(d), "+v"(s));
  return s;
}
// offsets 8/4/2/1: DPP row_shl:N -> lane n receives lane n+N within its row.
template<int N>
__device__ __forceinline__ unsigned dpp_shl_u(unsigned x) {
  return (unsigned)__builtin_amdgcn_update_dpp(0, (int)x, 0x100 | N, 0xF, 0xF, true);
}
__device__ __forceinline__ float pl_down32_f(float x) {
  return __uint_as_float(pl_down32_u(__float_as_uint(x)));
}
__device__ __forceinline__ float pl_down16_f(float x) {
  return __uint_as_float(pl_down16_u(__float_as_uint(x)));
}
template<int N>
__device__ __forceinline__ float dpp_shl_f(float x) {
  return __uint_as_float(dpp_shl_u<N>(__float_as_uint(x)));
}
__device__ __forceinline__ double pl_down32_d(double x) {
  unsigned lo = pl_down32_u((unsigned)__double2loint(x));
  unsigned hi = pl_down32_u((unsigned)__double2hiint(x));
  return __hiloint2double((int)hi, (int)lo);
}
__device__ __forceinline__ double pl_down16_d(double x) {
  unsigned lo = pl_down16_u((unsigned)__double2loint(x));
  unsigned hi = pl_down16_u((unsigned)__double2hiint(x));
  return __hiloint2double((int)hi, (int)lo);
}
template<int N>
__device__ __forceinline__ double dpp_shl_d(double x) {
  unsigned lo = dpp_shl_u<N>((unsigned)__double2loint(x));
  unsigned hi = dpp_shl_u<N>((unsigned)__double2hiint(x));
  return __hiloint2double((int)hi, (int)lo);
}
// lane-0 broadcast (all lanes active at every call site) -> readfirstlane.
__device__ __forceinline__ float bcast0_f(float x) {
  return __uint_as_float((unsigned)__builtin_amdgcn_readfirstlane((int)__float_as_uint(x)));
}
__device__ __forceinline__ int bcast0_i(int x) {
  return __builtin_amdgcn_readfirstlane(x);
}
__device__ __forceinline__ double bcast0_d(double x) {
  int lo = __builtin_amdgcn_readfirstlane(__double2loint(x));
  int hi = __builtin_amdgcn_readfirstlane(__double2hiint(x));
  return __hiloint2double(hi, lo);
}

// cross-wave barrier WITHOUT vmcnt drain: LDS writes visible (lgkmcnt) +
// s_barrier.
#define LGKM_BAR()                                                            \
  do {                                                                        \
    asm volatile("s_waitcnt lgkmcnt(0)" ::: "memory");                        \
    __builtin_amdgcn_s_barrier();                                             \
  } while (0)

// ---------------- fused 16-wave kernel (10 sampler + 6 gen) -----------------
// Sampler path: R23/R26/R27-validated step with ig = 2*wid + i. Gen path:
// step S+1's gumbels into s_gg[1-CUR]; 384 gen lanes; segment coverage
// seg0: [0,384)+[1152,1280), seg1: [384,768), seg2: [768,1152).
#define STEP_F(S, CUR, CC, CN)                                                \
  if (wid < NSW) {                                                            \
    const int step = (S);                                                     \
    /* this step's gumbels from LDS (published by prev step's barriers) */    \
    float GGl[NCPW];                                                          \
    _Pragma("unroll")                                                         \
    for (int i = 0; i < NCPW; ++i)                                            \
      GGl[i] = s_gg[CUR][(NCPW * wid + i) * 64 + lane];                       \
    /* prefetch next step's cand (registers) */                               \
    const int sn = (step + 1 < T_COLS) ? step + 1 : step;                     \
    _Pragma("unroll")                                                         \
    for (int i = 0; i < NCPW; ++i)                                            \
      CN[i] = candg[sn * KC + (NCPW * wid + i) * 64 + lane];                  \
    /* slide window state (lanes 0-15, per wave, identical values) */         \
    if (lane < 16) {                                                          \
      if (step > 0) {                                                         \
        double pw = (double)s_pi[step - 1];                                   \
        if ((c_last >> lane) & 1u) p1_d += pw;                                \
        pt_d += pw;                                                           \
      }                                                                       \
      if (step >= 33) {                                                       \
        double pw = (double)s_pi[step - 33];                                  \
        if (((uint32_t)s_cint[step - 33] >> lane) & 1u) p1_d -= pw;           \
        pt_d -= pw;                                                           \
      }                                                                       \
    }                                                                         \
    float Dl = (float)(pt_d - (p1_d + p1_d));                                 \
    double s0d = p1_d;                                                        \
    s0d += dpp_shl_d<1>(s0d);                                                 \
    s0d += dpp_shl_d<2>(s0d);                                                 \
    s0d += dpp_shl_d<4>(s0d);                                                 \
    s0d += dpp_shl_d<8>(s0d);                                                 \
    const float S0f  = bcast0_f((float)s0d);                                  \
    const float Pt16 = bcast0_f((float)(16.0 * pt_d));                        \
    {                                                                         \
      int n = lane >> 4, v = lane & 15;                                       \
      float d0 = __shfl(Dl, 4 * n + 0);                                       \
      float d1 = __shfl(Dl, 4 * n + 1);                                       \
      float d2 = __shfl(Dl, 4 * n + 2);                                       \
      float d3 = __shfl(Dl, 4 * n + 3);                                       \
      float t = 0.0f;                                                         \
      if (v & 1) t += d0;                                                     \
      if (v & 2) t += d1;                                                     \
      if (v & 4) t += d2;                                                     \
      if (v & 8) t += d3;                                                     \
      s_T[n][v] = t;                                                          \
    }                                                                         \
    __builtin_amdgcn_wave_barrier();                                          \
    const float pi_i   = s_pi[step];                                          \
    const float i_pf   = (float)step;                                         \
    const float factor = (step > 0) ? (i_pf / fminf(i_pf, 32.0f)) : 0.0f;     \
    float un[NCPW];                                                           \
    _Pragma("unroll")                                                         \
    for (int i = 0; i < NCPW; ++i) {                                          \
      uint32_t c = CC[i];                                                     \
      float sc = S0f + s_T[0][c & 15];                                        \
      sc += s_T[1][(c >> 4) & 15];                                            \
      sc += s_T[2][(c >> 8) & 15];                                            \
      sc += s_T[3][(c >> 12) & 15];                                           \
      float sv = Pt16 - sc;                                                   \
      int w = __popc(c);                                                      \
      int m = 16 * w - 256 + step;                                            \
      float sq  = (float)(m * m) * 0.00390625f;                               \
      float obk = (pi_i * sq) * 0.0625f;                                      \
      un[i] = -(obk + factor * (pi_i * sv));                                  \
    }                                                                         \
    float wmw = fmaxf(un[0], un[1]);                                          \
    s_cf[wid][lane] = wmw;                                                    \
    LGKM_BAR();                                                               \
    float wm = s_cf[0][lane];                                                 \
    _Pragma("unroll")                                                         \
    for (int w = 1; w < NSW; ++w) wm = fmaxf(wm, s_cf[w][lane]);              \
    wm = fmaxf(wm, pl_down32_f(wm));                                          \
    wm = fmaxf(wm, pl_down16_f(wm));                                          \
    wm = fmaxf(wm, dpp_shl_f<8>(wm));                                         \
    wm = fmaxf(wm, dpp_shl_f<4>(wm));                                         \
    wm = fmaxf(wm, dpp_shl_f<2>(wm));                                         \
    wm = fmaxf(wm, dpp_shl_f<1>(wm));                                         \
    wm = bcast0_f(wm);                                                        \
    /* exp partials: ig = 2*wid+i -> parity == i (a0 even-ig, a1 odd-ig) */   \
    double a0 = (double)expf(un[0] - wm);                                     \
    double a1 = (double)expf(un[1] - wm);                                     \
    s_cd[wid][lane] = a0 + a1;                                                \
    LGKM_BAR();                                                               \
    double sw = s_cd[0][lane];                                                \
    _Pragma("unroll")                                                         \
    for (int w = 1; w < NSW; ++w) sw = sw + s_cd[w][lane];                    \
    sw += pl_down32_d(sw);                                                    \
    sw += pl_down16_d(sw);                                                    \
    sw += dpp_shl_d<8>(sw);                                                   \
    sw += dpp_shl_d<4>(sw);                                                   \
    sw += dpp_shl_d<2>(sw);                                                   \
    sw += dpp_shl_d<1>(sw);                                                   \
    const float lsum = logf((float)bcast0_d(sw));                             \
    float bz; int bi; float bu;                                               \
    {                                                                         \
      bz = ((un[0] - wm) - lsum) + GGl[0];                                    \
      bi = ((64 * (NCPW * wid) + lane) << 16) | (int)CC[0];                   \
      bu = un[0];                                                             \
      {                                                                       \
        float zi = ((un[1] - wm) - lsum) + GGl[1];                            \
        int   ii = ((64 * (NCPW * wid + 1) + lane) << 16) | (int)CC[1];       \
        if (zi > bz || (zi == bz && ii < bi)) { bz = zi; bi = ii; bu = un[1]; }\
      }                                                                       \
    }                                                                         \
    s_cz[wid][lane] = bz; s_ci[wid][lane] = bi; s_cu[wid][lane] = bu;         \
    LGKM_BAR();                                                               \
    bz = s_cz[0][lane]; bi = s_ci[0][lane]; bu = s_cu[0][lane];               \
    _Pragma("unroll")                                                         \
    for (int w = 1; w < NSW; ++w) {                                           \
      float oz = s_cz[w][lane]; int oi = s_ci[w][lane];                       \
      float ou = s_cu[w][lane];                                               \
      if (oz > bz || (oz == bz && oi < bi)) { bz = oz; bi = oi; bu = ou; }    \
    }                                                                         \
    {                                                                         \
      float oz = pl_down32_f(bz); int oi = (int)pl_down32_u((unsigned)bi);    \
      float ou = pl_down32_f(bu);                                             \
      if (oz > bz || (oz == bz && oi < bi)) { bz = oz; bi = oi; bu = ou; }    \
    }                                                                         \
    {                                                                         \
      float oz = pl_down16_f(bz); int oi = (int)pl_down16_u((unsigned)bi);    \
      float ou = pl_down16_f(bu);                                             \
      if (oz > bz || (oz == bz && oi < bi)) { bz = oz; bi = oi; bu = ou; }    \
    }                                                                         \
    {                                                                         \
      float oz = dpp_shl_f<8>(bz); int oi = (int)dpp_shl_u<8>((unsigned)bi);  \
      float ou = dpp_shl_f<8>(bu);                                            \
      if (oz > bz || (oz == bz && oi < bi)) { bz = oz; bi = oi; bu = ou; }    \
    }                                                                         \
    {                                                                         \
      float oz = dpp_shl_f<4>(bz); int oi = (int)dpp_shl_u<4>((unsigned)bi);  \
      float ou = dpp_shl_f<4>(bu);                                            \
      if (oz > bz || (oz == bz && oi < bi)) { bz = oz; bi = oi; bu = ou; }    \
    }                                                                         \
    {                                                                         \
      float oz = dpp_shl_f<2>(bz); int oi = (int)dpp_shl_u<2>((unsigned)bi);  \
      float ou = dpp_shl_f<2>(bu);                                            \
      if (oz > bz || (oz == bz && oi < bi)) { bz = oz; bi = oi; bu = ou; }    \
    }                                                                         \
    {                                                                         \
      float oz = dpp_shl_f<1>(bz); int oi = (int)dpp_shl_u<1>((unsigned)bi);  \
      float ou = dpp_shl_f<1>(bu);                                            \
      if (oz > bz || (oz == bz && oi < bi)) { bz = oz; bi = oi; bu = ou; }    \
    }                                                                         \
    int wpk = bcast0_i(bi);                                                   \
    c_last = (uint32_t)wpk & 0xFFFFu;                                         \
    if (wid == 0 && lane == 0) {                                              \
      s_cint[step] = (unsigned short)c_last;                                  \
      lp_acc += (double)((bu - wm) - lsum);                                   \
    }                                                                         \
  } else {                                                                    \
    /* gen waves (6): step S+1's gumbels into s_gg[1-CUR]. */                 \
    const int SN = (S) + 1;                                                   \
    const int ggl = (wid - NSW) * 64 + lane;      /* 0..383 */                \
    if (SN < T_COLS) {                                                        \
      const uint32_t k0 = s_ks[SN][0], k1 = s_ks[SN][1];                      \
      s_gg[1 - (CUR)][ggl] = gumbel_at(k0, k1, (uint32_t)(b * KC + ggl));     \
      if (ggl < 128) {                                                        \
        int k = 1152 + ggl;                                                   \
        s_gg[1 - (CUR)][k] = gumbel_at(k0, k1, (uint32_t)(b * KC + k));       \
      }                                                                       \
    }                                                                         \
    LGKM_BAR();                                                               \
    if (SN < T_COLS) {                                                        \
      const uint32_t k0 = s_ks[SN][0], k1 = s_ks[SN][1];                      \
      int k = 384 + ggl;                                                      \
      s_gg[1 - (CUR)][k] = gumbel_at(k0, k1, (uint32_t)(b * KC + k));         \
    }                                                                         \
    LGKM_BAR();                                                               \
    if (SN < T_COLS) {                                                        \
      const uint32_t k0 = s_ks[SN][0], k1 = s_ks[SN][1];                      \
      int k = 768 + ggl;                                                      \
      s_gg[1 - (CUR)][k] = gumbel_at(k0, k1, (uint32_t)(b * KC + k));         \
    }                                                                         \
    LGKM_BAR();                                                               \
  }

__global__ void __launch_bounds__(NTHR, 1)
mrf_fused16(const float* __restrict__ pi, float* __restrict__ out,
            const unsigned short* __restrict__ candg) {
#pragma clang fp contract(off)
  const int b    = blockIdx.x;
  const int tid  = threadIdx.x;
  const int lane = tid & 63;
  const int wid  = tid >> 6;               // 0-9 sampler, 10-15 gen

  __shared__ float          s_pi[T_COLS];
  __shared__ unsigned short s_cint[T_COLS];
  __shared__ float          s_T[4][16];
  __shared__ float          s_cf[NSW][64];      // rmax partials
  __shared__ double         s_cd[NSW][64];      // exp-sum partials
  __shared__ float          s_cz[NSW][64];      // argmax z
  __shared__ int            s_ci[NSW][64];      // argmax idx
  __shared__ float          s_cu[NSW][64];      // argmax un
  __shared__ float          s_gg[2][KC];        // gumbel double buffer
  __shared__ uint32_t       s_ks[T_COLS][2];    // per-step k_samp keys

  for (int t = tid; t < T_COLS; t += NTHR) s_pi[t] = pi[t];
  if (tid < T_COLS) {
    uint32_t ks[2];
    derive_keys(tid, nullptr, ks, nullptr);
    s_ks[tid][0] = ks[0]; s_ks[tid][1] = ks[1];
  }
  __syncthreads();                          // publish s_pi, s_ks

  // sampler waves win issue arbitration; gen waves fill bubbles (T5).
  if (wid < NSW) __builtin_amdgcn_s_setprio(1);
  else           __builtin_amdgcn_s_setprio(0);

  double lp_acc = 0.0;                      // wave0 lane0 only
  uint32_t c_last = 0;
  double p1_d = 0.0, pt_d = 0.0;            // sliding window state (lanes<16)

  uint32_t cA[NCPW], cB[NCPW];

  // prologue: gen waves produce step-0 gumbels into buffer 0; sampler waves
  // prefetch step-0 cand into registers.
  if (wid >= NSW) {
    const int ggl = (wid - NSW) * 64 + lane;      // 0..383
    const uint32_t k0 = s_ks[0][0], k1 = s_ks[0][1];
    s_gg[0][ggl]       = gumbel_at(k0, k1, (uint32_t)(b * KC + ggl));
    s_gg[0][384 + ggl] = gumbel_at(k0, k1, (uint32_t)(b * KC + 384 + ggl));
    s_gg[0][768 + ggl] = gumbel_at(k0, k1, (uint32_t)(b * KC + 768 + ggl));
    if (ggl < 128)
      s_gg[0][1152 + ggl] = gumbel_at(k0, k1, (uint32_t)(b * KC + 1152 + ggl));
  } else {
#pragma unroll
    for (int i = 0; i < NCPW; ++i)
      cA[i] = candg[(NCPW * wid + i) * 64 + lane];
  }
  __syncthreads();                          // publish s_gg[0]

  for (int s2 = 0; s2 < T_COLS; s2 += 2) {
    STEP_F(s2,     0, cA, cB)
    STEP_F(s2 + 1, 1, cB, cA)
  }

  __syncthreads();
  // outputs (FP32): c_btls one-hot [B,T,L,S] then log_prob_b [B]
  for (int idx2 = tid; idx2 < T_COLS * 32; idx2 += NTHR) {
    int t    = idx2 >> 5;
    int rem  = idx2 & 31;
    int l    = rem >> 1;
    int sbit = rem & 1;
    uint32_t code = s_cint[t];
    int bit = (int)((code >> (15 - l)) & 1u);
    out[(size_t)b * 8192 + idx2] = (float)(sbit ? bit : (1 - bit));
  }
  if (tid == 0) {
    out[(size_t)B_ROWS * 8192 + b] = (float)(lp_acc / 256.0);
  }
}

// ---------------- legacy sequential kernel (fallback mode 0) ----------------
template<int MODE>
__global__ void __launch_bounds__(BLOCK_S)
mrf_seq_kernel(const float* __restrict__ pi, float* __restrict__ out,
               const float* __restrict__ gw,
               const unsigned short* __restrict__ candg) {
#pragma clang fp contract(off)
  const int b    = blockIdx.x;
  const int tid  = threadIdx.x;
  const bool has1 = tid < (KC - BLOCK_S);

  __shared__ float          s_pi[T_COLS];
  __shared__ unsigned short s_cand[KC];
  __shared__ float          s_unnorm[KC];
  __shared__ unsigned short s_cint[T_COLS];
  __shared__ int            s_dC[17][17];
  __shared__ int            s_gw0[17], s_gw1[17], s_gbase[17];
  __shared__ int            s_ngrp;
  __shared__ uint32_t       s_keys[6];
  __shared__ float          s_pw[WWIN];
  __shared__ unsigned short s_wc[WWIN];
  __shared__ float          s_redf[NWAVE_S];
  __shared__ double         s_redd[NWAVE_S];
  __shared__ int            s_redi[NWAVE_S];
  __shared__ float          s_bcast[2];

  for (int t = tid; t < T_COLS; t += BLOCK_S) s_pi[t] = pi[t];
  if (MODE == 0) {
    for (int i = tid; i < 289; i += BLOCK_S) s_dC[i/17][i%17] = dC[i/17][i%17];
  }
  double lp_acc = 0.0;
  __syncthreads();

  for (int step = 0; step < T_COLS; ++step) {
    if (tid == 0) {
      if (MODE == 1) {
        uint32_t ks[2];
        derive_keys(step, nullptr, ks, nullptr);
        s_keys[2] = ks[0]; s_keys[3] = ks[1];
      } else {
        uint32_t ks[2], k2[2];
        derive_keys(step, nullptr, ks, k2);
        s_keys[2] = ks[0]; s_keys[3] = ks[1];
        s_keys[4] = k2[0]; s_keys[5] = k2[1];
        int ws[17], am[17];
        for (int w = 0; w < 17; ++w) {
          int m = 16 * w - 256 + step;
          am[w] = m < 0 ? -m : m;
          ws[w] = w;
        }
        for (int a2 = 1; a2 < 17; ++a2) {
          int wvv = ws[a2], kv = am[wvv];
          int j2 = a2 - 1;
          while (j2 >= 0 && am[ws[j2]] > kv) { ws[j2 + 1] = ws[j2]; --j2; }
          ws[j2 + 1] = wvv;
        }
        int ng = 0, base = 0, idx = 0;
        while (idx < 17) {
          int w0 = ws[idx]; int a0v = am[w0]; int w1 = -1;
          if (idx + 1 < 17 && am[ws[idx + 1]] == a0v) { w1 = ws[idx + 1]; ++idx; }
          ++idx;
          s_gw0[ng] = w0; s_gw1[ng] = w1; s_gbase[ng] = base;
          base += dC[16][w0] + (w1 >= 0 ? dC[16][w1] : 0);
          ++ng;
          if (base >= PTOP) break;
        }
        s_ngrp = ng;
      }
    }
    if (tid < WWIN) {
      int win = step - WWIN + tid;
      s_pw[tid] = (win >= 0) ? s_pi[win] : 0.0f;
      s_wc[tid] = (win >= 0) ? s_cint[win] : (unsigned short)0;
    }
    __syncthreads();

    uint32_t c0, c1 = 0;
    if (MODE >= 1) {
      c0 = candg[step * KC + tid];
      if (has1) c1 = candg[step * KC + BLOCK_S + tid];
    } else {
      {
        int p = tid;
        int g = 0;
        for (int t2 = 1; t2 < s_ngrp; ++t2) if (s_gbase[t2] <= p) g = t2;
        int q  = p - s_gbase[g];
        int r0 = s_gw0[g], r1 = s_gw1[g];
        uint32_t code = 0;
        for (int pos = 15; pos >= 0; --pos) {
          int n0 = ((r0 >= 0 && r0 <= pos) ? s_dC[pos][r0] : 0)
                 + ((r1 >= 0 && r1 <= pos) ? s_dC[pos][r1] : 0);
          if (q >= n0) { q -= n0; code |= (1u << pos); --r0; if (r1 >= 0) --r1; }
        }
        c0 = code;
      }
      if (has1) {
        int t2 = tid;
        uint32_t a0, a1;
#if JAX_PARTITIONABLE
        tf_block(s_keys[4], s_keys[5], 0u, (uint32_t)t2, a0, a1);
        c1 = (a0 ^ a1) & 0xFFFFu;
#else
        if (t2 < 128) { tf_block(s_keys[4], s_keys[5], (uint32_t)t2, (uint32_t)(128 + t2), a0, a1);
                        c1 = a0 & 0xFFFFu; }
        else          { tf_block(s_keys[4], s_keys[5], (uint32_t)(t2 - 128), (uint32_t)t2, a0, a1);
                        c1 = a1 & 0xFFFFu; }
#endif
      }
    }
    s_cand[tid] = (unsigned short)c0;
    if (has1) s_cand[BLOCK_S + tid] = (unsigned short)c1;

    const float pi_i   = s_pi[step];
    const float i_pf   = (float)step;
    const float factor = (step > 0) ? (i_pf / fminf(i_pf, 32.0f)) : 0.0f;

    float un0, un1 = -3.402823466e+38f;
    {
      int w = __popc(c0);
      int m = 16 * w - 256 + step;
      float sq  = (float)(m * m) * 0.00390625f;
      float obk = (pi_i * sq) * 0.0625f;
      float s = 0.0f;
      for (int w2 = 0; w2 < WWIN; ++w2) {
        float ov = (float)(16 - __popc(c0 ^ (uint32_t)s_wc[w2]));
        s = s + s_pw[w2] * ov;
      }
      un0 = -(obk + factor * (pi_i * s));
    }
    if (has1) {
      int w = __popc(c1);
      int m = 16 * w - 256 + step;
      float sq  = (float)(m * m) * 0.00390625f;
      float obk = (pi_i * sq) * 0.0625f;
      float s = 0.0f;
      for (int w2 = 0; w2 < WWIN; ++w2) {
        float ov = (float)(16 - __popc(c1 ^ (uint32_t)s_wc[w2]));
        s = s + s_pw[w2] * ov;
      }
      un1 = -(obk + factor * (pi_i * s));
    }
    s_unnorm[tid] = un0;
    if (has1) s_unnorm[BLOCK_S + tid] = un1;

    float g0v = 0.0f, g1v = 0.0f;
    {
      const uint32_t ks0 = s_keys[2], ks1 = s_keys[3];
      g0v = gumbel_at(ks0, ks1, (uint32_t)(b * KC + tid));
      if (has1) g1v = gumbel_at(ks0, ks1, (uint32_t)(b * KC + BLOCK_S + tid));
    }

    float pmax = has1 ? fmaxf(un0, un1) : un0;
    for (int off = 32; off > 0; off >>= 1) pmax = fmaxf(pmax, __shfl_down(pmax, off));
    if ((tid & 63) == 0) s_redf[tid >> 6] = pmax;
    __syncthreads();
    if (tid == 0) {
      float mm = s_redf[0];
      for (int w2 = 1; w2 < NWAVE_S; ++w2) mm = fmaxf(mm, s_redf[w2]);
      s_bcast[0] = mm;
    }
    __syncthreads();
    const float rmax = s_bcast[0];

    double acc = (double)((float)exp((double)(un0 - rmax)));
    if (has1) acc += (double)((float)exp((double)(un1 - rmax)));
    for (int off = 32; off > 0; off >>= 1) acc += __shfl_down(acc, off);
    if ((tid & 63) == 0) s_redd[tid >> 6] = acc;
    __syncthreads();
    if (tid == 0) {
      double ss = 0.0;
      for (int w2 = 0; w2 < NWAVE_S; ++w2) ss += s_redd[w2];
      float sum_f = (float)ss;
      s_bcast[1] = (float)log((double)sum_f);
    }
    __syncthreads();
    const float lsum = s_bcast[1];

    float bz = ((un0 - rmax) - lsum) + g0v;
    int   bi = tid;
    if (has1) {
      float z1 = ((un1 - rmax) - lsum) + g1v;
      if (z1 > bz) { bz = z1; bi = BLOCK_S + tid; }
    }
    for (int off = 32; off > 0; off >>= 1) {
      float oz = __shfl_down(bz, off);
      int   oi = __shfl_down(bi, off);
      if (oz > bz || (oz == bz && oi < bi)) { bz = oz; bi = oi; }
    }
    if ((tid & 63) == 0) { s_redf[tid >> 6] = bz; s_redi[tid >> 6] = bi; }
    __syncthreads();
    if (tid == 0) {
      float bz2 = s_redf[0]; int bi2 = s_redi[0];
      for (int w2 = 1; w2 < NWAVE_S; ++w2) {
        if (s_redf[w2] > bz2 || (s_redf[w2] == bz2 && s_redi[w2] < bi2)) {
          bz2 = s_redf[w2]; bi2 = s_redi[w2];
        }
      }
      s_cint[step] = s_cand[bi2];
      float lpw = (s_unnorm[bi2] - rmax) - lsum;
      lp_acc += (double)lpw;
    }
    __syncthreads();
  }

  for (int idx2 = tid; idx2 < T_COLS * 32; idx2 += BLOCK_S) {
    int t    = idx2 >> 5;
    int rem  = idx2 & 31;
    int l    = rem >> 1;
    int sbit = rem & 1;
    uint32_t code = s_cint[t];
    int bit = (int)((code >> (15 - l)) & 1u);
    out[(size_t)b * 8192 + idx2] = (float)(sbit ? bit : (1 - bit));
  }
  if (tid == 0) {
    out[(size_t)B_ROWS * 8192 + b] = (float)(lp_acc / 256.0);
  }
}

extern "C" void kernel_launch(void* const* d_in, const int* in_sizes, int n_in,
                              void* d_out, int out_size, void* d_ws, size_t ws_size,
                              hipStream_t stream) {
  const float* pi = (const float*)d_in[0];
  float* out = (float*)d_out;

  const size_t cand_bytes = (size_t)T_COLS * KC * sizeof(unsigned short); // 655,360

  if (ws_size >= cand_bytes) {
    unsigned short* candg = (unsigned short*)d_ws;
    cand_kernel<<<dim3(T_COLS), dim3(256), 0, stream>>>(candg);
    mrf_fused16<<<dim3(B_ROWS), dim3(NTHR), 0, stream>>>(pi, out, candg);
  } else {
    mrf_seq_kernel<0><<<dim3(B_ROWS), dim3(BLOCK_S), 0, stream>>>(pi, out, nullptr, nullptr);
  }
}

// Round 16
// 834.011 us; speedup vs baseline: 1.3420x; 1.3420x over previous
//
#include <hip/hip_runtime.h>
#include <stdint.h>
#include <math.h>

// ---------------------------------------------------------------------------
// MRF codebook generator: bit-exact reproduction of the JAX reference.
// Round 29: REVERT to the R27 champion (836.7 us total, absmax 0.0).
//  - R28 (10 sampler x 2 cand + 6 gen, 16 waves) regressed to 1119 us:
//    combine loops read 10 partials (vs 4) at each of 3 barriers, the
//    duplicated scalar prelude ran in 10 waves (vs 4), and 4 waves/SIMD
//    crowded issue. Per-step cost ~ a*NCPW + b*NSW with b ~ 350-400 cy:
//    NSW=4 is near the minimum (R24/R26/R27/R28 bracket it).
//  - This file is the R27 kernel byte-for-byte: 12 waves = 4 sampler waves
//    x 5 candidates + 8 gen waves (1 gumbel per wave per segment), LDS
//    double-buffered gumbels, 3 LGKM barriers/step, setprio 1/0.
// Fallback: legacy mode-0 kernel kept.
// ---------------------------------------------------------------------------

#define JAX_PARTITIONABLE 1

#define T_COLS 256
#define B_ROWS 128
#define KC     1280
#define PTOP   1024
#define RRAND  256
#define WWIN   32
#define NCAND  20            // KC / 64
#define NWAVES 4             // sampler waves per block
#define NGW    8             // gen waves per block
#define NTHR   ((NWAVES + NGW) * 64)   // 768
#define NCPL   5             // candidates per lane per sampler wave
#define BLOCK_S 1024         // legacy fallback block
#define NWAVE_S (BLOCK_S / 64)

__device__ __constant__ int dC[17][17] = {
  {1},
  {1,1},
  {1,2,1},
  {1,3,3,1},
  {1,4,6,4,1},
  {1,5,10,10,5,1},
  {1,6,15,20,15,6,1},
  {1,7,21,35,35,21,7,1},
  {1,8,28,56,70,56,28,8,1},
  {1,9,36,84,126,126,84,36,9,1},
  {1,10,45,120,210,252,210,120,45,10,1},
  {1,11,55,165,330,462,462,330,165,55,11,1},
  {1,12,66,220,495,792,924,792,495,220,66,12,1},
  {1,13,78,286,715,1287,1716,1716,1287,715,286,78,13,1},
  {1,14,91,364,1001,2002,3003,3432,3003,2002,1001,364,91,14,1},
  {1,15,105,455,1365,3003,5005,6435,6435,5005,3003,1365,455,105,15,1},
  {1,16,120,560,1820,4368,8008,11440,12870,11440,8008,4368,1820,560,120,16,1}
};

// Threefry-2x32, 20 rounds, JAX key schedule.
__device__ __forceinline__ void tf_block(uint32_t k0, uint32_t k1,
                                         uint32_t x0, uint32_t x1,
                                         uint32_t& o0, uint32_t& o1) {
  uint32_t ks2 = k0 ^ k1 ^ 0x1BD11BDAu;
  x0 += k0; x1 += k1;
#define TFR(r) { x0 += x1; x1 = (x1 << (r)) | (x1 >> (32 - (r))); x1 ^= x0; }
  TFR(13) TFR(15) TFR(26) TFR(6)   x0 += k1;  x1 += ks2 + 1u;
  TFR(17) TFR(29) TFR(16) TFR(24)  x0 += ks2; x1 += k0 + 2u;
  TFR(13) TFR(15) TFR(26) TFR(6)   x0 += k0;  x1 += k1 + 3u;
  TFR(17) TFR(29) TFR(16) TFR(24)  x0 += k1;  x1 += ks2 + 4u;
  TFR(13) TFR(15) TFR(26) TFR(6)   x0 += ks2; x1 += k0 + 5u;
#undef TFR
  o0 = x0; o1 = x1;
}

// fold_in(key(42), step) -> k_rand/k_samp/randint-k2 per PRNG mode.
__device__ __forceinline__ void derive_keys(int step,
                                            uint32_t* krand, uint32_t* ksamp,
                                            uint32_t* k2) {
  uint32_t y0, y1;
  tf_block(0u, 42u, 0u, (uint32_t)step, y0, y1);
  uint32_t kr0 = y0, kr1 = y1;
#if JAX_PARTITIONABLE
  uint32_t r0, r1;
  tf_block(kr0, kr1, 0u, 0u, r0, r1);            // k_rand
  if (krand) { krand[0] = r0; krand[1] = r1; }
  if (ksamp) { tf_block(kr0, kr1, 0u, 1u, y0, y1); ksamp[0] = y0; ksamp[1] = y1; }
  if (k2)    { tf_block(r0, r1, 0u, 1u, y0, y1);  k2[0] = y0;  k2[1] = y1; }
#else
  uint32_t a0,a1,b0,b1;
  tf_block(kr0, kr1, 0u, 2u, a0, a1);
  tf_block(kr0, kr1, 1u, 3u, b0, b1);
  if (krand) { krand[0] = a0; krand[1] = b0; }
  if (ksamp) { ksamp[0] = a1; ksamp[1] = b1; }
  if (k2) {
    uint32_t c0,c1,d0,d1;
    tf_block(a0, b0, 0u, 2u, c0, c1);
    tf_block(a0, b0, 1u, 3u, d0, d1);
    k2[0] = c1; k2[1] = d1;
  }
#endif
}

// JAX uniform(tiny,1) -> gumbel, fp32 logs correctly-rounded-from-double.
__device__ __forceinline__ float gumbel_from_bits(uint32_t bits) {
  uint32_t fb = (bits >> 9) | 0x3f800000u;
  float f = __uint_as_float(fb) - 1.0f;
  float u = (f == 0.0f) ? 1.17549435e-38f : f;
  float l1 = (float)log((double)u);
  float l2 = (float)log((double)(-l1));
  return -l2;
}

__device__ __forceinline__ float gumbel_at(uint32_t ks0, uint32_t ks1, uint32_t j) {
  uint32_t g0, g1;
#if JAX_PARTITIONABLE
  tf_block(ks0, ks1, 0u, j, g0, g1);
  return gumbel_from_bits(g0 ^ g1);
#else
  uint32_t half = (uint32_t)(B_ROWS * KC / 2);
  if (j < half) { tf_block(ks0, ks1, j, j + half, g0, g1);  return gumbel_from_bits(g0); }
  else          { tf_block(ks0, ks1, j - half, j, g0, g1);  return gumbel_from_bits(g1); }
#endif
}

// ---------------- precompute kernel C: cand[step][k] ------------------------
__global__ void __launch_bounds__(256)
cand_kernel(unsigned short* __restrict__ candg) {
  const int step = blockIdx.x;
  const int tid  = threadIdx.x;
  __shared__ int s_dC[17][17];
  __shared__ int s_gw0[17], s_gw1[17], s_gbase[17];
  __shared__ int s_ngrp;
  __shared__ uint32_t s_k2[2];
  for (int i = tid; i < 289; i += 256) s_dC[i/17][i%17] = dC[i/17][i%17];
  if (tid == 0) {
    uint32_t k2[2];
    derive_keys(step, nullptr, nullptr, k2);
    s_k2[0] = k2[0]; s_k2[1] = k2[1];
    int ws[17], am[17];
    for (int w = 0; w < 17; ++w) {
      int m = 16 * w - 256 + step;
      am[w] = m < 0 ? -m : m;
      ws[w] = w;
    }
    for (int a2 = 1; a2 < 17; ++a2) {
      int wv = ws[a2], kv = am[wv];
      int j2 = a2 - 1;
      while (j2 >= 0 && am[ws[j2]] > kv) { ws[j2 + 1] = ws[j2]; --j2; }
      ws[j2 + 1] = wv;
    }
    int ng = 0, base = 0, idx = 0;
    while (idx < 17) {
      int w0 = ws[idx]; int a0v = am[w0]; int w1 = -1;
      if (idx + 1 < 17 && am[ws[idx + 1]] == a0v) { w1 = ws[idx + 1]; ++idx; }
      ++idx;
      s_gw0[ng] = w0; s_gw1[ng] = w1; s_gbase[ng] = base;
      base += dC[16][w0] + (w1 >= 0 ? dC[16][w1] : 0);
      ++ng;
      if (base >= PTOP) break;
    }
    s_ngrp = ng;
  }
  __syncthreads();
  for (int p = tid; p < PTOP; p += 256) {
    int g = 0;
    for (int t2 = 1; t2 < s_ngrp; ++t2) if (s_gbase[t2] <= p) g = t2;
    int q  = p - s_gbase[g];
    int r0 = s_gw0[g], r1 = s_gw1[g];
    uint32_t code = 0;
    for (int pos = 15; pos >= 0; --pos) {
      int n0 = ((r0 >= 0 && r0 <= pos) ? s_dC[pos][r0] : 0)
             + ((r1 >= 0 && r1 <= pos) ? s_dC[pos][r1] : 0);
      if (q >= n0) { q -= n0; code |= (1u << pos); --r0; if (r1 >= 0) --r1; }
    }
    candg[step * KC + p] = (unsigned short)code;
  }
  {
    int t2 = tid;
    uint32_t a0, a1;
#if JAX_PARTITIONABLE
    tf_block(s_k2[0], s_k2[1], 0u, (uint32_t)t2, a0, a1);
    candg[step * KC + PTOP + t2] = (unsigned short)((a0 ^ a1) & 0xFFFFu);
#else
    if (t2 < 128) { tf_block(s_k2[0], s_k2[1], (uint32_t)t2, (uint32_t)(128 + t2), a0, a1);
                    candg[step * KC + PTOP + t2] = (unsigned short)(a0 & 0xFFFFu); }
    else          { tf_block(s_k2[0], s_k2[1], (uint32_t)(t2 - 128), (uint32_t)t2, a0, a1);
                    candg[step * KC + PTOP + t2] = (unsigned short)(a1 & 0xFFFFu); }
#endif
  }
}

// ---------------- VALU-pipe cross-lane primitives ---------------------------
// offset 32: v_permlane32_swap_b32 with both operands = x -> vsrc result is
// [x.hi32, x.hi32]: lanes 0-31 receive lane i+32.
__device__ __forceinline__ unsigned pl_down32_u(unsigned x) {
  unsigned d = x, s = x;
  asm volatile("s_nop 1\n\tv_permlane32_swap_b32 %0, %1" : "+v"(d), "+v"(s));
  return s;
}
// offset 16: v_permlane16_swap_b32 -> lanes 0-15 get lane i+16.
__device__ __forceinline__ unsigned pl_down16_u(unsigned x) {
  unsigned d = x, s = x;
  asm volatile("s_nop 1\n\tv_permlane16_swap_b32 %0, %1" : "+v"(d), "+v"(s));
  return s;
}
// offsets 8/4/2/1: DPP row_shl:N -> lane n receives lane n+N within its row.
template<int N>
__device__ __forceinline__ unsigned dpp_shl_u(unsigned x) {
  return (unsigned)__builtin_amdgcn_update_dpp(0, (int)x, 0x100 | N, 0xF, 0xF, true);
}
__device__ __forceinline__ float pl_down32_f(float x) {
  return __uint_as_float(pl_down32_u(__float_as_uint(x)));
}
__device__ __forceinline__ float pl_down16_f(float x) {
  return __uint_as_float(pl_down16_u(__float_as_uint(x)));
}
template<int N>
__device__ __forceinline__ float dpp_shl_f(float x) {
  return __uint_as_float(dpp_shl_u<N>(__float_as_uint(x)));
}
__device__ __forceinline__ double pl_down32_d(double x) {
  unsigned lo = pl_down32_u((unsigned)__double2loint(x));
  unsigned hi = pl_down32_u((unsigned)__double2hiint(x));
  return __hiloint2double((int)hi, (int)lo);
}
__device__ __forceinline__ double pl_down16_d(double x) {
  unsigned lo = pl_down16_u((unsigned)__double2loint(x));
  unsigned hi = pl_down16_u((unsigned)__double2hiint(x));
  return __hiloint2double((int)hi, (int)lo);
}
template<int N>
__device__ __forceinline__ double dpp_shl_d(double x) {
  unsigned lo = dpp_shl_u<N>((unsigned)__double2loint(x));
  unsigned hi = dpp_shl_u<N>((unsigned)__double2hiint(x));
  return __hiloint2double((int)hi, (int)lo);
}
// lane-0 broadcast (all lanes active at every call site) -> readfirstlane.
__device__ __forceinline__ float bcast0_f(float x) {
  return __uint_as_float((unsigned)__builtin_amdgcn_readfirstlane((int)__float_as_uint(x)));
}
__device__ __forceinline__ int bcast0_i(int x) {
  return __builtin_amdgcn_readfirstlane(x);
}
__device__ __forceinline__ double bcast0_d(double x) {
  int lo = __builtin_amdgcn_readfirstlane(__double2loint(x));
  int hi = __builtin_amdgcn_readfirstlane(__double2hiint(x));
  return __hiloint2double(hi, lo);
}

// cross-wave barrier WITHOUT vmcnt drain: LDS writes visible (lgkmcnt) +
// s_barrier.
#define LGKM_BAR()                                                            \
  do {                                                                        \
    asm volatile("s_waitcnt lgkmcnt(0)" ::: "memory");                        \
    __builtin_amdgcn_s_barrier();                                             \
  } while (0)

// ---------------- fused 12-wave kernel (4 sampler + 8 gen) ------------------
// Sampler path: EXACT R23/R26-validated step. Gen path: step S+1's gumbels
// into s_gg[1-CUR]; 512 gen lanes -> 1 gumbel per wave per segment
// (seg0: k=ggl, seg1: k=512+ggl, seg2: k=1024+ggl if ggl<256).
#define STEP_F(S, CUR, CC, CN)                                                \
  if (wid < NWAVES) {                                                         \
    const int step = (S);                                                     \
    /* this step's gumbels from LDS (published by prev step's barriers) */    \
    float GGl[NCPL];                                                          \
    _Pragma("unroll")                                                         \
    for (int i = 0; i < NCPL; ++i)                                            \
      GGl[i] = s_gg[CUR][(NCPL * wid + i) * 64 + lane];                       \
    /* prefetch next step's cand (registers) */                               \
    const int sn = (step + 1 < T_COLS) ? step + 1 : step;                     \
    _Pragma("unroll")                                                         \
    for (int i = 0; i < NCPL; ++i)                                            \
      CN[i] = candg[sn * KC + (NCPL * wid + i) * 64 + lane];                  \
    /* slide window state (lanes 0-15, per wave, identical values) */         \
    if (lane < 16) {                                                          \
      if (step > 0) {                                                         \
        double pw = (double)s_pi[step - 1];                                   \
        if ((c_last >> lane) & 1u) p1_d += pw;                                \
        pt_d += pw;                                                           \
      }                                                                       \
      if (step >= 33) {                                                       \
        double pw = (double)s_pi[step - 33];                                  \
        if (((uint32_t)s_cint[step - 33] >> lane) & 1u) p1_d -= pw;           \
        pt_d -= pw;                                                           \
      }                                                                       \
    }                                                                         \
    float Dl = (float)(pt_d - (p1_d + p1_d));                                 \
    double s0d = p1_d;                                                        \
    s0d += dpp_shl_d<1>(s0d);                                                 \
    s0d += dpp_shl_d<2>(s0d);                                                 \
    s0d += dpp_shl_d<4>(s0d);                                                 \
    s0d += dpp_shl_d<8>(s0d);                                                 \
    const float S0f  = bcast0_f((float)s0d);                                  \
    const float Pt16 = bcast0_f((float)(16.0 * pt_d));                        \
    {                                                                         \
      int n = lane >> 4, v = lane & 15;                                       \
      float d0 = __shfl(Dl, 4 * n + 0);                                       \
      float d1 = __shfl(Dl, 4 * n + 1);                                       \
      float d2 = __shfl(Dl, 4 * n + 2);                                       \
      float d3 = __shfl(Dl, 4 * n + 3);                                       \
      float t = 0.0f;                                                         \
      if (v & 1) t += d0;                                                     \
      if (v & 2) t += d1;                                                     \
      if (v & 4) t += d2;                                                     \
      if (v & 8) t += d3;                                                     \
      s_T[n][v] = t;                                                          \
    }                                                                         \
    __builtin_amdgcn_wave_barrier();                                          \
    const float pi_i   = s_pi[step];                                          \
    const float i_pf   = (float)step;                                         \
    const float factor = (step > 0) ? (i_pf / fminf(i_pf, 32.0f)) : 0.0f;     \
    float un[NCPL];                                                           \
    _Pragma("unroll")                                                         \
    for (int i = 0; i < NCPL; ++i) {                                          \
      uint32_t c = CC[i];                                                     \
      float sc = S0f + s_T[0][c & 15];                                        \
      sc += s_T[1][(c >> 4) & 15];                                            \
      sc += s_T[2][(c >> 8) & 15];                                            \
      sc += s_T[3][(c >> 12) & 15];                                           \
      float sv = Pt16 - sc;                                                   \
      int w = __popc(c);                                                      \
      int m = 16 * w - 256 + step;                                            \
      float sq  = (float)(m * m) * 0.00390625f;                               \
      float obk = (pi_i * sq) * 0.0625f;                                      \
      un[i] = -(obk + factor * (pi_i * sv));                                  \
    }                                                                         \
    float wmw = fmaxf(fmaxf(fmaxf(un[0], un[1]), fmaxf(un[2], un[3])),        \
                      un[4]);                                                 \
    s_cf[wid][lane] = wmw;                                                    \
    LGKM_BAR();                                                               \
    float wm = fmaxf(fmaxf(s_cf[0][lane], s_cf[1][lane]),                     \
                     fmaxf(s_cf[2][lane], s_cf[3][lane]));                    \
    wm = fmaxf(wm, pl_down32_f(wm));                                          \
    wm = fmaxf(wm, pl_down16_f(wm));                                          \
    wm = fmaxf(wm, dpp_shl_f<8>(wm));                                         \
    wm = fmaxf(wm, dpp_shl_f<4>(wm));                                         \
    wm = fmaxf(wm, dpp_shl_f<2>(wm));                                         \
    wm = fmaxf(wm, dpp_shl_f<1>(wm));                                         \
    wm = bcast0_f(wm);                                                        \
    double a0 = 0.0, a1 = 0.0;                                                \
    _Pragma("unroll")                                                         \
    for (int i = 0; i < NCPL; ++i) {                                          \
      float e = expf(un[i] - wm);                                             \
      if ((NCPL * wid + i) & 1) a1 += (double)e; else a0 += (double)e;        \
    }                                                                         \
    s_cd[wid][lane] = a0 + a1;                                                \
    LGKM_BAR();                                                               \
    double sw = ((s_cd[0][lane] + s_cd[1][lane]) + s_cd[2][lane])             \
                + s_cd[3][lane];                                              \
    sw += pl_down32_d(sw);                                                    \
    sw += pl_down16_d(sw);                                                    \
    sw += dpp_shl_d<8>(sw);                                                   \
    sw += dpp_shl_d<4>(sw);                                                   \
    sw += dpp_shl_d<2>(sw);                                                   \
    sw += dpp_shl_d<1>(sw);                                                   \
    const float lsum = logf((float)bcast0_d(sw));                             \
    float bz; int bi; float bu;                                               \
    {                                                                         \
      bz = ((un[0] - wm) - lsum) + GGl[0];                                    \
      bi = ((64 * (NCPL * wid) + lane) << 16) | (int)CC[0];                   \
      bu = un[0];                                                             \
      _Pragma("unroll")                                                       \
      for (int i = 1; i < NCPL; ++i) {                                        \
        float zi = ((un[i] - wm) - lsum) + GGl[i];                            \
        int   ii = ((64 * (NCPL * wid + i) + lane) << 16) | (int)CC[i];       \
        if (zi > bz || (zi == bz && ii < bi)) { bz = zi; bi = ii; bu = un[i]; }\
      }                                                                       \
    }                                                                         \
    s_cz[wid][lane] = bz; s_ci[wid][lane] = bi; s_cu[wid][lane] = bu;         \
    LGKM_BAR();                                                               \
    bz = s_cz[0][lane]; bi = s_ci[0][lane]; bu = s_cu[0][lane];               \
    _Pragma("unroll")                                                         \
    for (int w = 1; w < NWAVES; ++w) {                                        \
      float oz = s_cz[w][lane]; int oi = s_ci[w][lane];                       \
      float ou = s_cu[w][lane];                                               \
      if (oz > bz || (oz == bz && oi < bi)) { bz = oz; bi = oi; bu = ou; }    \
    }                                                                         \
    {                                                                         \
      float oz = pl_down32_f(bz); int oi = (int)pl_down32_u((unsigned)bi);    \
      float ou = pl_down32_f(bu);                                             \
      if (oz > bz || (oz == bz && oi < bi)) { bz = oz; bi = oi; bu = ou; }    \
    }                                                                         \
    {                                                                         \
      float oz = pl_down16_f(bz); int oi = (int)pl_down16_u((unsigned)bi);    \
      float ou = pl_down16_f(bu);                                             \
      if (oz > bz || (oz == bz && oi < bi)) { bz = oz; bi = oi; bu = ou; }    \
    }                                                                         \
    {                                                                         \
      float oz = dpp_shl_f<8>(bz); int oi = (int)dpp_shl_u<8>((unsigned)bi);  \
      float ou = dpp_shl_f<8>(bu);                                            \
      if (oz > bz || (oz == bz && oi < bi)) { bz = oz; bi = oi; bu = ou; }    \
    }                                                                         \
    {                                                                         \
      float oz = dpp_shl_f<4>(bz); int oi = (int)dpp_shl_u<4>((unsigned)bi);  \
      float ou = dpp_shl_f<4>(bu);                                            \
      if (oz > bz || (oz == bz && oi < bi)) { bz = oz; bi = oi; bu = ou; }    \
    }                                                                         \
    {                                                                         \
      float oz = dpp_shl_f<2>(bz); int oi = (int)dpp_shl_u<2>((unsigned)bi);  \
      float ou = dpp_shl_f<2>(bu);                                            \
      if (oz > bz || (oz == bz && oi < bi)) { bz = oz; bi = oi; bu = ou; }    \
    }                                                                         \
    {                                                                         \
      float oz = dpp_shl_f<1>(bz); int oi = (int)dpp_shl_u<1>((unsigned)bi);  \
      float ou = dpp_shl_f<1>(bu);                                            \
      if (oz > bz || (oz == bz && oi < bi)) { bz = oz; bi = oi; bu = ou; }    \
    }                                                                         \
    int wpk = bcast0_i(bi);                                                   \
    c_last = (uint32_t)wpk & 0xFFFFu;                                         \
    if (wid == 0 && lane == 0) {                                              \
      s_cint[step] = (unsigned short)c_last;                                  \
      lp_acc += (double)((bu - wm) - lsum);                                   \
    }                                                                         \
  } else {                                                                    \
    /* gen waves (8): step S+1's gumbels into s_gg[1-CUR]; one gumbel per    \
       wave per segment. */                                                   \
    const int SN = (S) + 1;                                                   \
    const int ggl = (wid - NWAVES) * 64 + lane;   /* 0..511 */                \
    if (SN < T_COLS) {                                                        \
      const uint32_t k0 = s_ks[SN][0], k1 = s_ks[SN][1];                      \
      s_gg[1 - (CUR)][ggl] = gumbel_at(k0, k1, (uint32_t)(b * KC + ggl));     \
    }                                                                         \
    LGKM_BAR();                                                               \
    if (SN < T_COLS) {                                                        \
      const uint32_t k0 = s_ks[SN][0], k1 = s_ks[SN][1];                      \
      int k = 512 + ggl;                                                      \
      s_gg[1 - (CUR)][k] = gumbel_at(k0, k1, (uint32_t)(b * KC + k));         \
    }                                                                         \
    LGKM_BAR();                                                               \
    if (SN < T_COLS && ggl < 256) {                                           \
      const uint32_t k0 = s_ks[SN][0], k1 = s_ks[SN][1];                      \
      int k = 1024 + ggl;                                                     \
      s_gg[1 - (CUR)][k] = gumbel_at(k0, k1, (uint32_t)(b * KC + k));         \
    }                                                                         \
    LGKM_BAR();                                                               \
  }

__global__ void __launch_bounds__(NTHR, 1)
mrf_fused12(const float* __restrict__ pi, float* __restrict__ out,
            const unsigned short* __restrict__ candg) {
#pragma clang fp contract(off)
  const int b    = blockIdx.x;
  const int tid  = threadIdx.x;
  const int lane = tid & 63;
  const int wid  = tid >> 6;               // 0-3 sampler, 4-11 gen

  __shared__ float          s_pi[T_COLS];
  __shared__ unsigned short s_cint[T_COLS];
  __shared__ float          s_T[4][16];
  __shared__ float          s_cf[NWAVES][64];   // rmax partials
  __shared__ double         s_cd[NWAVES][64];   // exp-sum partials
  __shared__ float          s_cz[NWAVES][64];   // argmax z
  __shared__ int            s_ci[NWAVES][64];   // argmax idx
  __shared__ float          s_cu[NWAVES][64];   // argmax un
  __shared__ float          s_gg[2][KC];        // gumbel double buffer
  __shared__ uint32_t       s_ks[T_COLS][2];    // per-step k_samp keys

  for (int t = tid; t < T_COLS; t += NTHR) s_pi[t] = pi[t];
  if (tid < T_COLS) {
    uint32_t ks[2];
    derive_keys(tid, nullptr, ks, nullptr);
    s_ks[tid][0] = ks[0]; s_ks[tid][1] = ks[1];
  }
  __syncthreads();                          // publish s_pi, s_ks

  // sampler waves win issue arbitration; gen waves fill bubbles (T5).
  if (wid < NWAVES) __builtin_amdgcn_s_setprio(1);
  else              __builtin_amdgcn_s_setprio(0);

  double lp_acc = 0.0;                      // wave0 lane0 only
  uint32_t c_last = 0;
  double p1_d = 0.0, pt_d = 0.0;            // sliding window state (lanes<16)

  uint32_t cA[NCPL], cB[NCPL];

  // prologue: gen waves produce step-0 gumbels into buffer 0; sampler waves
  // prefetch step-0 cand into registers.
  if (wid >= NWAVES) {
    const int ggl = (wid - NWAVES) * 64 + lane;   // 0..511
    const uint32_t k0 = s_ks[0][0], k1 = s_ks[0][1];
    s_gg[0][ggl]       = gumbel_at(k0, k1, (uint32_t)(b * KC + ggl));
    s_gg[0][512 + ggl] = gumbel_at(k0, k1, (uint32_t)(b * KC + 512 + ggl));
    if (ggl < 256)
      s_gg[0][1024 + ggl] = gumbel_at(k0, k1, (uint32_t)(b * KC + 1024 + ggl));
  } else {
#pragma unroll
    for (int i = 0; i < NCPL; ++i)
      cA[i] = candg[(NCPL * wid + i) * 64 + lane];
  }
  __syncthreads();                          // publish s_gg[0]

  for (int s2 = 0; s2 < T_COLS; s2 += 2) {
    STEP_F(s2,     0, cA, cB)
    STEP_F(s2 + 1, 1, cB, cA)
  }

  __syncthreads();
  // outputs (FP32): c_btls one-hot [B,T,L,S] then log_prob_b [B]
  for (int idx2 = tid; idx2 < T_COLS * 32; idx2 += NTHR) {
    int t    = idx2 >> 5;
    int rem  = idx2 & 31;
    int l    = rem >> 1;
    int sbit = rem & 1;
    uint32_t code = s_cint[t];
    int bit = (int)((code >> (15 - l)) & 1u);
    out[(size_t)b * 8192 + idx2] = (float)(sbit ? bit : (1 - bit));
  }
  if (tid == 0) {
    out[(size_t)B_ROWS * 8192 + b] = (float)(lp_acc / 256.0);
  }
}

// ---------------- legacy sequential kernel (fallback mode 0) ----------------
template<int MODE>
__global__ void __launch_bounds__(BLOCK_S)
mrf_seq_kernel(const float* __restrict__ pi, float* __restrict__ out,
               const float* __restrict__ gw,
               const unsigned short* __restrict__ candg) {
#pragma clang fp contract(off)
  const int b    = blockIdx.x;
  const int tid  = threadIdx.x;
  const bool has1 = tid < (KC - BLOCK_S);

  __shared__ float          s_pi[T_COLS];
  __shared__ unsigned short s_cand[KC];
  __shared__ float          s_unnorm[KC];
  __shared__ unsigned short s_cint[T_COLS];
  __shared__ int            s_dC[17][17];
  __shared__ int            s_gw0[17], s_gw1[17], s_gbase[17];
  __shared__ int            s_ngrp;
  __shared__ uint32_t       s_keys[6];
  __shared__ float          s_pw[WWIN];
  __shared__ unsigned short s_wc[WWIN];
  __shared__ float          s_redf[NWAVE_S];
  __shared__ double         s_redd[NWAVE_S];
  __shared__ int            s_redi[NWAVE_S];
  __shared__ float          s_bcast[2];

  for (int t = tid; t < T_COLS; t += BLOCK_S) s_pi[t] = pi[t];
  if (MODE == 0) {
    for (int i = tid; i < 289; i += BLOCK_S) s_dC[i/17][i%17] = dC[i/17][i%17];
  }
  double lp_acc = 0.0;
  __syncthreads();

  for (int step = 0; step < T_COLS; ++step) {
    if (tid == 0) {
      if (MODE == 1) {
        uint32_t ks[2];
        derive_keys(step, nullptr, ks, nullptr);
        s_keys[2] = ks[0]; s_keys[3] = ks[1];
      } else {
        uint32_t ks[2], k2[2];
        derive_keys(step, nullptr, ks, k2);
        s_keys[2] = ks[0]; s_keys[3] = ks[1];
        s_keys[4] = k2[0]; s_keys[5] = k2[1];
        int ws[17], am[17];
        for (int w = 0; w < 17; ++w) {
          int m = 16 * w - 256 + step;
          am[w] = m < 0 ? -m : m;
          ws[w] = w;
        }
        for (int a2 = 1; a2 < 17; ++a2) {
          int wvv = ws[a2], kv = am[wvv];
          int j2 = a2 - 1;
          while (j2 >= 0 && am[ws[j2]] > kv) { ws[j2 + 1] = ws[j2]; --j2; }
          ws[j2 + 1] = wvv;
        }
        int ng = 0, base = 0, idx = 0;
        while (idx < 17) {
          int w0 = ws[idx]; int a0v = am[w0]; int w1 = -1;
          if (idx + 1 < 17 && am[ws[idx + 1]] == a0v) { w1 = ws[idx + 1]; ++idx; }
          ++idx;
          s_gw0[ng] = w0; s_gw1[ng] = w1; s_gbase[ng] = base;
          base += dC[16][w0] + (w1 >= 0 ? dC[16][w1] : 0);
          ++ng;
          if (base >= PTOP) break;
        }
        s_ngrp = ng;
      }
    }
    if (tid < WWIN) {
      int win = step - WWIN + tid;
      s_pw[tid] = (win >= 0) ? s_pi[win] : 0.0f;
      s_wc[tid] = (win >= 0) ? s_cint[win] : (unsigned short)0;
    }
    __syncthreads();

    uint32_t c0, c1 = 0;
    if (MODE >= 1) {
      c0 = candg[step * KC + tid];
      if (has1) c1 = candg[step * KC + BLOCK_S + tid];
    } else {
      {
        int p = tid;
        int g = 0;
        for (int t2 = 1; t2 < s_ngrp; ++t2) if (s_gbase[t2] <= p) g = t2;
        int q  = p - s_gbase[g];
        int r0 = s_gw0[g], r1 = s_gw1[g];
        uint32_t code = 0;
        for (int pos = 15; pos >= 0; --pos) {
          int n0 = ((r0 >= 0 && r0 <= pos) ? s_dC[pos][r0] : 0)
                 + ((r1 >= 0 && r1 <= pos) ? s_dC[pos][r1] : 0);
          if (q >= n0) { q -= n0; code |= (1u << pos); --r0; if (r1 >= 0) --r1; }
        }
        c0 = code;
      }
      if (has1) {
        int t2 = tid;
        uint32_t a0, a1;
#if JAX_PARTITIONABLE
        tf_block(s_keys[4], s_keys[5], 0u, (uint32_t)t2, a0, a1);
        c1 = (a0 ^ a1) & 0xFFFFu;
#else
        if (t2 < 128) { tf_block(s_keys[4], s_keys[5], (uint32_t)t2, (uint32_t)(128 + t2), a0, a1);
                        c1 = a0 & 0xFFFFu; }
        else          { tf_block(s_keys[4], s_keys[5], (uint32_t)(t2 - 128), (uint32_t)t2, a0, a1);
                        c1 = a1 & 0xFFFFu; }
#endif
      }
    }
    s_cand[tid] = (unsigned short)c0;
    if (has1) s_cand[BLOCK_S + tid] = (unsigned short)c1;

    const float pi_i   = s_pi[step];
    const float i_pf   = (float)step;
    const float factor = (step > 0) ? (i_pf / fminf(i_pf, 32.0f)) : 0.0f;

    float un0, un1 = -3.402823466e+38f;
    {
      int w = __popc(c0);
      int m = 16 * w - 256 + step;
      float sq  = (float)(m * m) * 0.00390625f;
      float obk = (pi_i * sq) * 0.0625f;
      float s = 0.0f;
      for (int w2 = 0; w2 < WWIN; ++w2) {
        float ov = (float)(16 - __popc(c0 ^ (uint32_t)s_wc[w2]));
        s = s + s_pw[w2] * ov;
      }
      un0 = -(obk + factor * (pi_i * s));
    }
    if (has1) {
      int w = __popc(c1);
      int m = 16 * w - 256 + step;
      float sq  = (float)(m * m) * 0.00390625f;
      float obk = (pi_i * sq) * 0.0625f;
      float s = 0.0f;
      for (int w2 = 0; w2 < WWIN; ++w2) {
        float ov = (float)(16 - __popc(c1 ^ (uint32_t)s_wc[w2]));
        s = s + s_pw[w2] * ov;
      }
      un1 = -(obk + factor * (pi_i * s));
    }
    s_unnorm[tid] = un0;
    if (has1) s_unnorm[BLOCK_S + tid] = un1;

    float g0v = 0.0f, g1v = 0.0f;
    {
      const uint32_t ks0 = s_keys[2], ks1 = s_keys[3];
      g0v = gumbel_at(ks0, ks1, (uint32_t)(b * KC + tid));
      if (has1) g1v = gumbel_at(ks0, ks1, (uint32_t)(b * KC + BLOCK_S + tid));
    }

    float pmax = has1 ? fmaxf(un0, un1) : un0;
    for (int off = 32; off > 0; off >>= 1) pmax = fmaxf(pmax, __shfl_down(pmax, off));
    if ((tid & 63) == 0) s_redf[tid >> 6] = pmax;
    __syncthreads();
    if (tid == 0) {
      float mm = s_redf[0];
      for (int w2 = 1; w2 < NWAVE_S; ++w2) mm = fmaxf(mm, s_redf[w2]);
      s_bcast[0] = mm;
    }
    __syncthreads();
    const float rmax = s_bcast[0];

    double acc = (double)((float)exp((double)(un0 - rmax)));
    if (has1) acc += (double)((float)exp((double)(un1 - rmax)));
    for (int off = 32; off > 0; off >>= 1) acc += __shfl_down(acc, off);
    if ((tid & 63) == 0) s_redd[tid >> 6] = acc;
    __syncthreads();
    if (tid == 0) {
      double ss = 0.0;
      for (int w2 = 0; w2 < NWAVE_S; ++w2) ss += s_redd[w2];
      float sum_f = (float)ss;
      s_bcast[1] = (float)log((double)sum_f);
    }
    __syncthreads();
    const float lsum = s_bcast[1];

    float bz = ((un0 - rmax) - lsum) + g0v;
    int   bi = tid;
    if (has1) {
      float z1 = ((un1 - rmax) - lsum) + g1v;
      if (z1 > bz) { bz = z1; bi = BLOCK_S + tid; }
    }
    for (int off = 32; off > 0; off >>= 1) {
      float oz = __shfl_down(bz, off);
      int   oi = __shfl_down(bi, off);
      if (oz > bz || (oz == bz && oi < bi)) { bz = oz; bi = oi; }
    }
    if ((tid & 63) == 0) { s_redf[tid >> 6] = bz; s_redi[tid >> 6] = bi; }
    __syncthreads();
    if (tid == 0) {
      float bz2 = s_redf[0]; int bi2 = s_redi[0];
      for (int w2 = 1; w2 < NWAVE_S; ++w2) {
        if (s_redf[w2] > bz2 || (s_redf[w2] == bz2 && s_redi[w2] < bi2)) {
          bz2 = s_redf[w2]; bi2 = s_redi[w2];
        }
      }
      s_cint[step] = s_cand[bi2];
      float lpw = (s_unnorm[bi2] - rmax) - lsum;
      lp_acc += (double)lpw;
    }
    __syncthreads();
  }

  for (int idx2 = tid; idx2 < T_COLS * 32; idx2 += BLOCK_S) {
    int t    = idx2 >> 5;
    int rem  = idx2 & 31;
    int l    = rem >> 1;
    int sbit = rem & 1;
    uint32_t code = s_cint[t];
    int bit = (int)((code >> (15 - l)) & 1u);
    out[(size_t)b * 8192 + idx2] = (float)(sbit ? bit : (1 - bit));
  }
  if (tid == 0) {
    out[(size_t)B_ROWS * 8192 + b] = (float)(lp_acc / 256.0);
  }
}

extern "C" void kernel_launch(void* const* d_in, const int* in_sizes, int n_in,
                              void* d_out, int out_size, void* d_ws, size_t ws_size,
                              hipStream_t stream) {
  const float* pi = (const float*)d_in[0];
  float* out = (float*)d_out;

  const size_t cand_bytes = (size_t)T_COLS * KC * sizeof(unsigned short); // 655,360

  if (ws_size >= cand_bytes) {
    unsigned short* candg = (unsigned short*)d_ws;
    cand_kernel<<<dim3(T_COLS), dim3(256), 0, stream>>>(candg);
    mrf_fused12<<<dim3(B_ROWS), dim3(NTHR), 0, stream>>>(pi, out, candg);
  } else {
    mrf_seq_kernel<0><<<dim3(B_ROWS), dim3(BLOCK_S), 0, stream>>>(pi, out, nullptr, nullptr);
  }
}

// Round 17
// 738.960 us; speedup vs baseline: 1.5146x; 1.1286x over previous
//
#include <hip/hip_runtime.h>
#include <stdint.h>
#include <math.h>

// ---------------------------------------------------------------------------
// MRF codebook generator: bit-exact reproduction of the JAX reference.
// Round 30: hybrid — idle half of the chip pre-produces second-half gumbels.
//  - R27/R29 champion (834 us): step = sampler 5500 cy + gen ~2300 cy of
//    f64-log pipe occupancy on the shared SIMDs (exact-numerics-bound).
//  - New: grid 256. Blocks 0-127 = EXACT R27 fused sampler. Blocks 128-255
//    = producers: block 128+b generates batch b's gumbels for steps
//    128..255 (656 KB each, ~130 us on their own CUs), then ONE
//    threadfence + release-store of done[b] and retire.
//    Sampler gen waves: steps <128 compute as before; steps >=128 LOAD
//    from the producer table (one-time all-lane acquire-spin at the
//    SN==128 prefetch — producer finished ~280 us earlier).
//  - R18/R19 failure modes absent: one-time handoff (not per-step), no
//    SIMD sharing (1 block/CU x 256 CUs by capacity), producers retire.
//  - Gumbel bits identical (same gumbel_at/keys/j via f32 table); sampler
//    arithmetic untouched -> absmax 0.0 lineage preserved.
// Fallbacks: pure-fused (gw2=nullptr, grid 128) if workspace small;
// legacy mode-0 kernel kept.
// ---------------------------------------------------------------------------

#define JAX_PARTITIONABLE 1

#define T_COLS 256
#define B_ROWS 128
#define HALF   128           // steps >= HALF come from the producer table
#define KC     1280
#define PTOP   1024
#define RRAND  256
#define WWIN   32
#define NCAND  20            // KC / 64
#define NWAVES 4             // sampler waves per block
#define NGW    8             // gen waves per block
#define NTHR   ((NWAVES + NGW) * 64)   // 768
#define NCPL   5             // candidates per lane per sampler wave
#define BLOCK_S 1024         // legacy fallback block
#define NWAVE_S (BLOCK_S / 64)

__device__ __constant__ int dC[17][17] = {
  {1},
  {1,1},
  {1,2,1},
  {1,3,3,1},
  {1,4,6,4,1},
  {1,5,10,10,5,1},
  {1,6,15,20,15,6,1},
  {1,7,21,35,35,21,7,1},
  {1,8,28,56,70,56,28,8,1},
  {1,9,36,84,126,126,84,36,9,1},
  {1,10,45,120,210,252,210,120,45,10,1},
  {1,11,55,165,330,462,462,330,165,55,11,1},
  {1,12,66,220,495,792,924,792,495,220,66,12,1},
  {1,13,78,286,715,1287,1716,1716,1287,715,286,78,13,1},
  {1,14,91,364,1001,2002,3003,3432,3003,2002,1001,364,91,14,1},
  {1,15,105,455,1365,3003,5005,6435,6435,5005,3003,1365,455,105,15,1},
  {1,16,120,560,1820,4368,8008,11440,12870,11440,8008,4368,1820,560,120,16,1}
};

// Threefry-2x32, 20 rounds, JAX key schedule.
__device__ __forceinline__ void tf_block(uint32_t k0, uint32_t k1,
                                         uint32_t x0, uint32_t x1,
                                         uint32_t& o0, uint32_t& o1) {
  uint32_t ks2 = k0 ^ k1 ^ 0x1BD11BDAu;
  x0 += k0; x1 += k1;
#define TFR(r) { x0 += x1; x1 = (x1 << (r)) | (x1 >> (32 - (r))); x1 ^= x0; }
  TFR(13) TFR(15) TFR(26) TFR(6)   x0 += k1;  x1 += ks2 + 1u;
  TFR(17) TFR(29) TFR(16) TFR(24)  x0 += ks2; x1 += k0 + 2u;
  TFR(13) TFR(15) TFR(26) TFR(6)   x0 += k0;  x1 += k1 + 3u;
  TFR(17) TFR(29) TFR(16) TFR(24)  x0 += k1;  x1 += ks2 + 4u;
  TFR(13) TFR(15) TFR(26) TFR(6)   x0 += ks2; x1 += k0 + 5u;
#undef TFR
  o0 = x0; o1 = x1;
}

// fold_in(key(42), step) -> k_rand/k_samp/randint-k2 per PRNG mode.
__device__ __forceinline__ void derive_keys(int step,
                                            uint32_t* krand, uint32_t* ksamp,
                                            uint32_t* k2) {
  uint32_t y0, y1;
  tf_block(0u, 42u, 0u, (uint32_t)step, y0, y1);
  uint32_t kr0 = y0, kr1 = y1;
#if JAX_PARTITIONABLE
  uint32_t r0, r1;
  tf_block(kr0, kr1, 0u, 0u, r0, r1);            // k_rand
  if (krand) { krand[0] = r0; krand[1] = r1; }
  if (ksamp) { tf_block(kr0, kr1, 0u, 1u, y0, y1); ksamp[0] = y0; ksamp[1] = y1; }
  if (k2)    { tf_block(r0, r1, 0u, 1u, y0, y1);  k2[0] = y0;  k2[1] = y1; }
#else
  uint32_t a0,a1,b0,b1;
  tf_block(kr0, kr1, 0u, 2u, a0, a1);
  tf_block(kr0, kr1, 1u, 3u, b0, b1);
  if (krand) { krand[0] = a0; krand[1] = b0; }
  if (ksamp) { ksamp[0] = a1; ksamp[1] = b1; }
  if (k2) {
    uint32_t c0,c1,d0,d1;
    tf_block(a0, b0, 0u, 2u, c0, c1);
    tf_block(a0, b0, 1u, 3u, d0, d1);
    k2[0] = c1; k2[1] = d1;
  }
#endif
}

// JAX uniform(tiny,1) -> gumbel, fp32 logs correctly-rounded-from-double.
__device__ __forceinline__ float gumbel_from_bits(uint32_t bits) {
  uint32_t fb = (bits >> 9) | 0x3f800000u;
  float f = __uint_as_float(fb) - 1.0f;
  float u = (f == 0.0f) ? 1.17549435e-38f : f;
  float l1 = (float)log((double)u);
  float l2 = (float)log((double)(-l1));
  return -l2;
}

__device__ __forceinline__ float gumbel_at(uint32_t ks0, uint32_t ks1, uint32_t j) {
  uint32_t g0, g1;
#if JAX_PARTITIONABLE
  tf_block(ks0, ks1, 0u, j, g0, g1);
  return gumbel_from_bits(g0 ^ g1);
#else
  uint32_t half = (uint32_t)(B_ROWS * KC / 2);
  if (j < half) { tf_block(ks0, ks1, j, j + half, g0, g1);  return gumbel_from_bits(g0); }
  else          { tf_block(ks0, ks1, j - half, j, g0, g1);  return gumbel_from_bits(g1); }
#endif
}

// ---------------- precompute kernel C: cand[step][k] ------------------------
__global__ void __launch_bounds__(256)
cand_kernel(unsigned short* __restrict__ candg) {
  const int step = blockIdx.x;
  const int tid  = threadIdx.x;
  __shared__ int s_dC[17][17];
  __shared__ int s_gw0[17], s_gw1[17], s_gbase[17];
  __shared__ int s_ngrp;
  __shared__ uint32_t s_k2[2];
  for (int i = tid; i < 289; i += 256) s_dC[i/17][i%17] = dC[i/17][i%17];
  if (tid == 0) {
    uint32_t k2[2];
    derive_keys(step, nullptr, nullptr, k2);
    s_k2[0] = k2[0]; s_k2[1] = k2[1];
    int ws[17], am[17];
    for (int w = 0; w < 17; ++w) {
      int m = 16 * w - 256 + step;
      am[w] = m < 0 ? -m : m;
      ws[w] = w;
    }
    for (int a2 = 1; a2 < 17; ++a2) {
      int wv = ws[a2], kv = am[wv];
      int j2 = a2 - 1;
      while (j2 >= 0 && am[ws[j2]] > kv) { ws[j2 + 1] = ws[j2]; --j2; }
      ws[j2 + 1] = wv;
    }
    int ng = 0, base = 0, idx = 0;
    while (idx < 17) {
      int w0 = ws[idx]; int a0v = am[w0]; int w1 = -1;
      if (idx + 1 < 17 && am[ws[idx + 1]] == a0v) { w1 = ws[idx + 1]; ++idx; }
      ++idx;
      s_gw0[ng] = w0; s_gw1[ng] = w1; s_gbase[ng] = base;
      base += dC[16][w0] + (w1 >= 0 ? dC[16][w1] : 0);
      ++ng;
      if (base >= PTOP) break;
    }
    s_ngrp = ng;
  }
  __syncthreads();
  for (int p = tid; p < PTOP; p += 256) {
    int g = 0;
    for (int t2 = 1; t2 < s_ngrp; ++t2) if (s_gbase[t2] <= p) g = t2;
    int q  = p - s_gbase[g];
    int r0 = s_gw0[g], r1 = s_gw1[g];
    uint32_t code = 0;
    for (int pos = 15; pos >= 0; --pos) {
      int n0 = ((r0 >= 0 && r0 <= pos) ? s_dC[pos][r0] : 0)
             + ((r1 >= 0 && r1 <= pos) ? s_dC[pos][r1] : 0);
      if (q >= n0) { q -= n0; code |= (1u << pos); --r0; if (r1 >= 0) --r1; }
    }
    candg[step * KC + p] = (unsigned short)code;
  }
  {
    int t2 = tid;
    uint32_t a0, a1;
#if JAX_PARTITIONABLE
    tf_block(s_k2[0], s_k2[1], 0u, (uint32_t)t2, a0, a1);
    candg[step * KC + PTOP + t2] = (unsigned short)((a0 ^ a1) & 0xFFFFu);
#else
    if (t2 < 128) { tf_block(s_k2[0], s_k2[1], (uint32_t)t2, (uint32_t)(128 + t2), a0, a1);
                    candg[step * KC + PTOP + t2] = (unsigned short)(a0 & 0xFFFFu); }
    else          { tf_block(s_k2[0], s_k2[1], (uint32_t)(t2 - 128), (uint32_t)t2, a0, a1);
                    candg[step * KC + PTOP + t2] = (unsigned short)(a1 & 0xFFFFu); }
#endif
  }
}

// ---------------- VALU-pipe cross-lane primitives ---------------------------
// offset 32: v_permlane32_swap_b32 with both operands = x -> vsrc result is
// [x.hi32, x.hi32]: lanes 0-31 receive lane i+32.
__device__ __forceinline__ unsigned pl_down32_u(unsigned x) {
  unsigned d = x, s = x;
  asm volatile("s_nop 1\n\tv_permlane32_swap_b32 %0, %1" : "+v"(d), "+v"(s));
  return s;
}
// offset 16: v_permlane16_swap_b32 -> lanes 0-15 get lane i+16.
__device__ __forceinline__ unsigned pl_down16_u(unsigned x) {
  unsigned d = x, s = x;
  asm volatile("s_nop 1\n\tv_permlane16_swap_b32 %0, %1" : "+v"(d), "+v"(s));
  return s;
}
// offsets 8/4/2/1: DPP row_shl:N -> lane n receives lane n+N within its row.
template<int N>
__device__ __forceinline__ unsigned dpp_shl_u(unsigned x) {
  return (unsigned)__builtin_amdgcn_update_dpp(0, (int)x, 0x100 | N, 0xF, 0xF, true);
}
__device__ __forceinline__ float pl_down32_f(float x) {
  return __uint_as_float(pl_down32_u(__float_as_uint(x)));
}
__device__ __forceinline__ float pl_down16_f(float x) {
  return __uint_as_float(pl_down16_u(__float_as_uint(x)));
}
template<int N>
__device__ __forceinline__ float dpp_shl_f(float x) {
  return __uint_as_float(dpp_shl_u<N>(__float_as_uint(x)));
}
__device__ __forceinline__ double pl_down32_d(double x) {
  unsigned lo = pl_down32_u((unsigned)__double2loint(x));
  unsigned hi = pl_down32_u((unsigned)__double2hiint(x));
  return __hiloint2double((int)hi, (int)lo);
}
__device__ __forceinline__ double pl_down16_d(double x) {
  unsigned lo = pl_down16_u((unsigned)__double2loint(x));
  unsigned hi = pl_down16_u((unsigned)__double2hiint(x));
  return __hiloint2double((int)hi, (int)lo);
}
template<int N>
__device__ __forceinline__ double dpp_shl_d(double x) {
  unsigned lo = dpp_shl_u<N>((unsigned)__double2loint(x));
  unsigned hi = dpp_shl_u<N>((unsigned)__double2hiint(x));
  return __hiloint2double((int)hi, (int)lo);
}
// lane-0 broadcast (all lanes active at every call site) -> readfirstlane.
__device__ __forceinline__ float bcast0_f(float x) {
  return __uint_as_float((unsigned)__builtin_amdgcn_readfirstlane((int)__float_as_uint(x)));
}
__device__ __forceinline__ int bcast0_i(int x) {
  return __builtin_amdgcn_readfirstlane(x);
}
__device__ __forceinline__ double bcast0_d(double x) {
  int lo = __builtin_amdgcn_readfirstlane(__double2loint(x));
  int hi = __builtin_amdgcn_readfirstlane(__double2hiint(x));
  return __hiloint2double(hi, lo);
}

// cross-wave barrier WITHOUT vmcnt drain: LDS writes visible (lgkmcnt) +
// s_barrier.
#define LGKM_BAR()                                                            \
  do {                                                                        \
    asm volatile("s_waitcnt lgkmcnt(0)" ::: "memory");                        \
    __builtin_amdgcn_s_barrier();                                             \
  } while (0)

// ---------------- hybrid 12-wave kernel (4 sampler + 8 gen/load) ------------
// Sampler path: EXACT R27/R29-validated step. Gen path: step S+1's gumbels
// into s_gg[1-CUR] — computed for SN < HALF, LOADED from the producer
// table gw2 for SN >= HALF (one-time all-lane acquire-spin at SN==HALF).
#define STEP_F(S, CUR, CC, CN)                                                \
  if (wid < NWAVES) {                                                         \
    const int step = (S);                                                     \
    /* this step's gumbels from LDS (published by prev step's barriers) */    \
    float GGl[NCPL];                                                          \
    _Pragma("unroll")                                                         \
    for (int i = 0; i < NCPL; ++i)                                            \
      GGl[i] = s_gg[CUR][(NCPL * wid + i) * 64 + lane];                       \
    /* prefetch next step's cand (registers) */                               \
    const int sn = (step + 1 < T_COLS) ? step + 1 : step;                     \
    _Pragma("unroll")                                                         \
    for (int i = 0; i < NCPL; ++i)                                            \
      CN[i] = candg[sn * KC + (NCPL * wid + i) * 64 + lane];                  \
    /* slide window state (lanes 0-15, per wave, identical values) */         \
    if (lane < 16) {                                                          \
      if (step > 0) {                                                         \
        double pw = (double)s_pi[step - 1];                                   \
        if ((c_last >> lane) & 1u) p1_d += pw;                                \
        pt_d += pw;                                                           \
      }                                                                       \
      if (step >= 33) {                                                       \
        double pw = (double)s_pi[step - 33];                                  \
        if (((uint32_t)s_cint[step - 33] >> lane) & 1u) p1_d -= pw;           \
        pt_d -= pw;                                                           \
      }                                                                       \
    }                                                                         \
    float Dl = (float)(pt_d - (p1_d + p1_d));                                 \
    double s0d = p1_d;                                                        \
    s0d += dpp_shl_d<1>(s0d);                                                 \
    s0d += dpp_shl_d<2>(s0d);                                                 \
    s0d += dpp_shl_d<4>(s0d);                                                 \
    s0d += dpp_shl_d<8>(s0d);                                                 \
    const float S0f  = bcast0_f((float)s0d);                                  \
    const float Pt16 = bcast0_f((float)(16.0 * pt_d));                        \
    {                                                                         \
      int n = lane >> 4, v = lane & 15;                                       \
      float d0 = __shfl(Dl, 4 * n + 0);                                       \
      float d1 = __shfl(Dl, 4 * n + 1);                                       \
      float d2 = __shfl(Dl, 4 * n + 2);                                       \
      float d3 = __shfl(Dl, 4 * n + 3);                                       \
      float t = 0.0f;                                                         \
      if (v & 1) t += d0;                                                     \
      if (v & 2) t += d1;                                                     \
      if (v & 4) t += d2;                                                     \
      if (v & 8) t += d3;                                                     \
      s_T[n][v] = t;                                                          \
    }                                                                         \
    __builtin_amdgcn_wave_barrier();                                          \
    const float pi_i   = s_pi[step];                                          \
    const float i_pf   = (float)step;                                         \
    const float factor = (step > 0) ? (i_pf / fminf(i_pf, 32.0f)) : 0.0f;     \
    float un[NCPL];                                                           \
    _Pragma("unroll")                                                         \
    for (int i = 0; i < NCPL; ++i) {                                          \
      uint32_t c = CC[i];                                                     \
      float sc = S0f + s_T[0][c & 15];                                        \
      sc += s_T[1][(c >> 4) & 15];                                            \
      sc += s_T[2][(c >> 8) & 15];                                            \
      sc += s_T[3][(c >> 12) & 15];                                           \
      float sv = Pt16 - sc;                                                   \
      int w = __popc(c);                                                      \
      int m = 16 * w - 256 + step;                                            \
      float sq  = (float)(m * m) * 0.00390625f;                               \
      float obk = (pi_i * sq) * 0.0625f;                                      \
      un[i] = -(obk + factor * (pi_i * sv));                                  \
    }                                                                         \
    float wmw = fmaxf(fmaxf(fmaxf(un[0], un[1]), fmaxf(un[2], un[3])),        \
                      un[4]);                                                 \
    s_cf[wid][lane] = wmw;                                                    \
    LGKM_BAR();                                                               \
    float wm = fmaxf(fmaxf(s_cf[0][lane], s_cf[1][lane]),                     \
                     fmaxf(s_cf[2][lane], s_cf[3][lane]));                    \
    wm = fmaxf(wm, pl_down32_f(wm));                                          \
    wm = fmaxf(wm, pl_down16_f(wm));                                          \
    wm = fmaxf(wm, dpp_shl_f<8>(wm));                                         \
    wm = fmaxf(wm, dpp_shl_f<4>(wm));                                         \
    wm = fmaxf(wm, dpp_shl_f<2>(wm));                                         \
    wm = fmaxf(wm, dpp_shl_f<1>(wm));                                         \
    wm = bcast0_f(wm);                                                        \
    double a0 = 0.0, a1 = 0.0;                                                \
    _Pragma("unroll")                                                         \
    for (int i = 0; i < NCPL; ++i) {                                          \
      float e = expf(un[i] - wm);                                             \
      if ((NCPL * wid + i) & 1) a1 += (double)e; else a0 += (double)e;        \
    }                                                                         \
    s_cd[wid][lane] = a0 + a1;                                                \
    LGKM_BAR();                                                               \
    double sw = ((s_cd[0][lane] + s_cd[1][lane]) + s_cd[2][lane])             \
                + s_cd[3][lane];                                              \
    sw += pl_down32_d(sw);                                                    \
    sw += pl_down16_d(sw);                                                    \
    sw += dpp_shl_d<8>(sw);                                                   \
    sw += dpp_shl_d<4>(sw);                                                   \
    sw += dpp_shl_d<2>(sw);                                                   \
    sw += dpp_shl_d<1>(sw);                                                   \
    const float lsum = logf((float)bcast0_d(sw));                             \
    float bz; int bi; float bu;                                               \
    {                                                                         \
      bz = ((un[0] - wm) - lsum) + GGl[0];                                    \
      bi = ((64 * (NCPL * wid) + lane) << 16) | (int)CC[0];                   \
      bu = un[0];                                                             \
      _Pragma("unroll")                                                       \
      for (int i = 1; i < NCPL; ++i) {                                        \
        float zi = ((un[i] - wm) - lsum) + GGl[i];                            \
        int   ii = ((64 * (NCPL * wid + i) + lane) << 16) | (int)CC[i];       \
        if (zi > bz || (zi == bz && ii < bi)) { bz = zi; bi = ii; bu = un[i]; }\
      }                                                                       \
    }                                                                         \
    s_cz[wid][lane] = bz; s_ci[wid][lane] = bi; s_cu[wid][lane] = bu;         \
    LGKM_BAR();                                                               \
    bz = s_cz[0][lane]; bi = s_ci[0][lane]; bu = s_cu[0][lane];               \
    _Pragma("unroll")                                                         \
    for (int w = 1; w < NWAVES; ++w) {                                        \
      float oz = s_cz[w][lane]; int oi = s_ci[w][lane];                       \
      float ou = s_cu[w][lane];                                               \
      if (oz > bz || (oz == bz && oi < bi)) { bz = oz; bi = oi; bu = ou; }    \
    }                                                                         \
    {                                                                         \
      float oz = pl_down32_f(bz); int oi = (int)pl_down32_u((unsigned)bi);    \
      float ou = pl_down32_f(bu);                                             \
      if (oz > bz || (oz == bz && oi < bi)) { bz = oz; bi = oi; bu = ou; }    \
    }                                                                         \
    {                                                                         \
      float oz = pl_down16_f(bz); int oi = (int)pl_down16_u((unsigned)bi);    \
      float ou = pl_down16_f(bu);                                             \
      if (oz > bz || (oz == bz && oi < bi)) { bz = oz; bi = oi; bu = ou; }    \
    }                                                                         \
    {                                                                         \
      float oz = dpp_shl_f<8>(bz); int oi = (int)dpp_shl_u<8>((unsigned)bi);  \
      float ou = dpp_shl_f<8>(bu);                                            \
      if (oz > bz || (oz == bz && oi < bi)) { bz = oz; bi = oi; bu = ou; }    \
    }                                                                         \
    {                                                                         \
      float oz = dpp_shl_f<4>(bz); int oi = (int)dpp_shl_u<4>((unsigned)bi);  \
      float ou = dpp_shl_f<4>(bu);                                            \
      if (oz > bz || (oz == bz && oi < bi)) { bz = oz; bi = oi; bu = ou; }    \
    }                                                                         \
    {                                                                         \
      float oz = dpp_shl_f<2>(bz); int oi = (int)dpp_shl_u<2>((unsigned)bi);  \
      float ou = dpp_shl_f<2>(bu);                                            \
      if (oz > bz || (oz == bz && oi < bi)) { bz = oz; bi = oi; bu = ou; }    \
    }                                                                         \
    {                                                                         \
      float oz = dpp_shl_f<1>(bz); int oi = (int)dpp_shl_u<1>((unsigned)bi);  \
      float ou = dpp_shl_f<1>(bu);                                            \
      if (oz > bz || (oz == bz && oi < bi)) { bz = oz; bi = oi; bu = ou; }    \
    }                                                                         \
    int wpk = bcast0_i(bi);                                                   \
    c_last = (uint32_t)wpk & 0xFFFFu;                                         \
    if (wid == 0 && lane == 0) {                                              \
      s_cint[step] = (unsigned short)c_last;                                  \
      lp_acc += (double)((bu - wm) - lsum);                                   \
    }                                                                         \
  } else {                                                                    \
    /* gen waves (8): step S+1's gumbels into s_gg[1-CUR]; one value per    \
       wave per segment. SN < HALF: compute. SN >= HALF (with gw2): load    \
       from the producer table (one-time acquire-spin at SN==HALF). */        \
    const int SN = (S) + 1;                                                   \
    const int ggl = (wid - NWAVES) * 64 + lane;   /* 0..511 */                \
    const bool ld = (gw2 != nullptr) && (SN >= HALF);                         \
    if (SN < T_COLS) {                                                        \
      if (!ld) {                                                              \
        const uint32_t k0 = s_ks[SN][0], k1 = s_ks[SN][1];                    \
        s_gg[1 - (CUR)][ggl] = gumbel_at(k0, k1, (uint32_t)(b * KC + ggl));   \
      } else {                                                                \
        if (SN == HALF) {                                                     \
          while (__hip_atomic_load(&done[b], __ATOMIC_ACQUIRE,                \
                                   __HIP_MEMORY_SCOPE_AGENT) == 0)            \
            __builtin_amdgcn_s_sleep(16);                                     \
        }                                                                     \
        s_gg[1 - (CUR)][ggl] =                                                \
            gw2[((size_t)b * HALF + (SN - HALF)) * KC + ggl];                 \
      }                                                                       \
    }                                                                         \
    LGKM_BAR();                                                               \
    if (SN < T_COLS) {                                                        \
      int k = 512 + ggl;                                                      \
      if (!ld) {                                                              \
        const uint32_t k0 = s_ks[SN][0], k1 = s_ks[SN][1];                    \
        s_gg[1 - (CUR)][k] = gumbel_at(k0, k1, (uint32_t)(b * KC + k));       \
      } else {                                                                \
        s_gg[1 - (CUR)][k] =                                                  \
            gw2[((size_t)b * HALF + (SN - HALF)) * KC + k];                   \
      }                                                                       \
    }                                                                         \
    LGKM_BAR();                                                               \
    if (SN < T_COLS && ggl < 256) {                                           \
      int k = 1024 + ggl;                                                     \
      if (!ld) {                                                              \
        const uint32_t k0 = s_ks[SN][0], k1 = s_ks[SN][1];                    \
        s_gg[1 - (CUR)][k] = gumbel_at(k0, k1, (uint32_t)(b * KC + k));       \
      } else {                                                                \
        s_gg[1 - (CUR)][k] =                                                  \
            gw2[((size_t)b * HALF + (SN - HALF)) * KC + k];                   \
      }                                                                       \
    }                                                                         \
    LGKM_BAR();                                                               \
  }

__global__ void __launch_bounds__(NTHR, 1)
mrf_hybrid(const float* __restrict__ pi, float* __restrict__ out,
           const unsigned short* __restrict__ candg,
           float* __restrict__ gw2, int* __restrict__ done) {
#pragma clang fp contract(off)
  const int bid  = blockIdx.x;
  const int tid  = threadIdx.x;
  const int lane = tid & 63;
  const int wid  = tid >> 6;               // 0-3 sampler, 4-11 gen

  __shared__ float          s_pi[T_COLS];
  __shared__ unsigned short s_cint[T_COLS];
  __shared__ float          s_T[4][16];
  __shared__ float          s_cf[NWAVES][64];   // rmax partials
  __shared__ double         s_cd[NWAVES][64];   // exp-sum partials
  __shared__ float          s_cz[NWAVES][64];   // argmax z
  __shared__ int            s_ci[NWAVES][64];   // argmax idx
  __shared__ float          s_cu[NWAVES][64];   // argmax un
  __shared__ float          s_gg[2][KC];        // gumbel double buffer
  __shared__ uint32_t       s_ks[T_COLS][2];    // per-step k_samp keys

  if (bid >= B_ROWS) {
    // ---------------- producer block: batch pb, steps HALF..255 ----------
    const int pb = bid - B_ROWS;
    if (tid < T_COLS) {
      uint32_t ks[2];
      derive_keys(tid, nullptr, ks, nullptr);
      s_ks[tid][0] = ks[0]; s_ks[tid][1] = ks[1];
    }
    __syncthreads();
    for (int s = HALF; s < T_COLS; ++s) {
      const uint32_t k0 = s_ks[s][0], k1 = s_ks[s][1];
      for (int k = tid; k < KC; k += NTHR)
        gw2[((size_t)pb * HALF + (s - HALF)) * KC + k] =
            gumbel_at(k0, k1, (uint32_t)(pb * KC + k));
    }
    __syncthreads();   // all waves' stores issued (vmcnt drained per-wave)
    if (tid == 0) {
      __threadfence(); // device-scope publish of the table
      __hip_atomic_store(&done[pb], 1, __ATOMIC_RELEASE,
                         __HIP_MEMORY_SCOPE_AGENT);
    }
    return;
  }

  // ---------------- sampler/consumer block ------------------------------
  const int b = bid;

  for (int t = tid; t < T_COLS; t += NTHR) s_pi[t] = pi[t];
  if (tid < T_COLS) {
    uint32_t ks[2];
    derive_keys(tid, nullptr, ks, nullptr);
    s_ks[tid][0] = ks[0]; s_ks[tid][1] = ks[1];
  }
  __syncthreads();                          // publish s_pi, s_ks

  // sampler waves win issue arbitration; gen waves fill bubbles (T5).
  if (wid < NWAVES) __builtin_amdgcn_s_setprio(1);
  else              __builtin_amdgcn_s_setprio(0);

  double lp_acc = 0.0;                      // wave0 lane0 only
  uint32_t c_last = 0;
  double p1_d = 0.0, pt_d = 0.0;            // sliding window state (lanes<16)

  uint32_t cA[NCPL], cB[NCPL];

  // prologue: gen waves produce step-0 gumbels into buffer 0; sampler waves
  // prefetch step-0 cand into registers.
  if (wid >= NWAVES) {
    const int ggl = (wid - NWAVES) * 64 + lane;   // 0..511
    const uint32_t k0 = s_ks[0][0], k1 = s_ks[0][1];
    s_gg[0][ggl]       = gumbel_at(k0, k1, (uint32_t)(b * KC + ggl));
    s_gg[0][512 + ggl] = gumbel_at(k0, k1, (uint32_t)(b * KC + 512 + ggl));
    if (ggl < 256)
      s_gg[0][1024 + ggl] = gumbel_at(k0, k1, (uint32_t)(b * KC + 1024 + ggl));
  } else {
#pragma unroll
    for (int i = 0; i < NCPL; ++i)
      cA[i] = candg[(NCPL * wid + i) * 64 + lane];
  }
  __syncthreads();                          // publish s_gg[0]

  for (int s2 = 0; s2 < T_COLS; s2 += 2) {
    STEP_F(s2,     0, cA, cB)
    STEP_F(s2 + 1, 1, cB, cA)
  }

  __syncthreads();
  // outputs (FP32): c_btls one-hot [B,T,L,S] then log_prob_b [B]
  for (int idx2 = tid; idx2 < T_COLS * 32; idx2 += NTHR) {
    int t    = idx2 >> 5;
    int rem  = idx2 & 31;
    int l    = rem >> 1;
    int sbit = rem & 1;
    uint32_t code = s_cint[t];
    int bit = (int)((code >> (15 - l)) & 1u);
    out[(size_t)b * 8192 + idx2] = (float)(sbit ? bit : (1 - bit));
  }
  if (tid == 0) {
    out[(size_t)B_ROWS * 8192 + b] = (float)(lp_acc / 256.0);
  }
}

// ---------------- legacy sequential kernel (fallback mode 0) ----------------
template<int MODE>
__global__ void __launch_bounds__(BLOCK_S)
mrf_seq_kernel(const float* __restrict__ pi, float* __restrict__ out,
               const float* __restrict__ gw,
               const unsigned short* __restrict__ candg) {
#pragma clang fp contract(off)
  const int b    = blockIdx.x;
  const int tid  = threadIdx.x;
  const bool has1 = tid < (KC - BLOCK_S);

  __shared__ float          s_pi[T_COLS];
  __shared__ unsigned short s_cand[KC];
  __shared__ float          s_unnorm[KC];
  __shared__ unsigned short s_cint[T_COLS];
  __shared__ int            s_dC[17][17];
  __shared__ int            s_gw0[17], s_gw1[17], s_gbase[17];
  __shared__ int            s_ngrp;
  __shared__ uint32_t       s_keys[6];
  __shared__ float          s_pw[WWIN];
  __shared__ unsigned short s_wc[WWIN];
  __shared__ float          s_redf[NWAVE_S];
  __shared__ double         s_redd[NWAVE_S];
  __shared__ int            s_redi[NWAVE_S];
  __shared__ float          s_bcast[2];

  for (int t = tid; t < T_COLS; t += BLOCK_S) s_pi[t] = pi[t];
  if (MODE == 0) {
    for (int i = tid; i < 289; i += BLOCK_S) s_dC[i/17][i%17] = dC[i/17][i%17];
  }
  double lp_acc = 0.0;
  __syncthreads();

  for (int step = 0; step < T_COLS; ++step) {
    if (tid == 0) {
      if (MODE == 1) {
        uint32_t ks[2];
        derive_keys(step, nullptr, ks, nullptr);
        s_keys[2] = ks[0]; s_keys[3] = ks[1];
      } else {
        uint32_t ks[2], k2[2];
        derive_keys(step, nullptr, ks, k2);
        s_keys[2] = ks[0]; s_keys[3] = ks[1];
        s_keys[4] = k2[0]; s_keys[5] = k2[1];
        int ws[17], am[17];
        for (int w = 0; w < 17; ++w) {
          int m = 16 * w - 256 + step;
          am[w] = m < 0 ? -m : m;
          ws[w] = w;
        }
        for (int a2 = 1; a2 < 17; ++a2) {
          int wvv = ws[a2], kv = am[wvv];
          int j2 = a2 - 1;
          while (j2 >= 0 && am[ws[j2]] > kv) { ws[j2 + 1] = ws[j2]; --j2; }
          ws[j2 + 1] = wvv;
        }
        int ng = 0, base = 0, idx = 0;
        while (idx < 17) {
          int w0 = ws[idx]; int a0v = am[w0]; int w1 = -1;
          if (idx + 1 < 17 && am[ws[idx + 1]] == a0v) { w1 = ws[idx + 1]; ++idx; }
          ++idx;
          s_gw0[ng] = w0; s_gw1[ng] = w1; s_gbase[ng] = base;
          base += dC[16][w0] + (w1 >= 0 ? dC[16][w1] : 0);
          ++ng;
          if (base >= PTOP) break;
        }
        s_ngrp = ng;
      }
    }
    if (tid < WWIN) {
      int win = step - WWIN + tid;
      s_pw[tid] = (win >= 0) ? s_pi[win] : 0.0f;
      s_wc[tid] = (win >= 0) ? s_cint[win] : (unsigned short)0;
    }
    __syncthreads();

    uint32_t c0, c1 = 0;
    if (MODE >= 1) {
      c0 = candg[step * KC + tid];
      if (has1) c1 = candg[step * KC + BLOCK_S + tid];
    } else {
      {
        int p = tid;
        int g = 0;
        for (int t2 = 1; t2 < s_ngrp; ++t2) if (s_gbase[t2] <= p) g = t2;
        int q  = p - s_gbase[g];
        int r0 = s_gw0[g], r1 = s_gw1[g];
        uint32_t code = 0;
        for (int pos = 15; pos >= 0; --pos) {
          int n0 = ((r0 >= 0 && r0 <= pos) ? s_dC[pos][r0] : 0)
                 + ((r1 >= 0 && r1 <= pos) ? s_dC[pos][r1] : 0);
          if (q >= n0) { q -= n0; code |= (1u << pos); --r0; if (r1 >= 0) --r1; }
        }
        c0 = code;
      }
      if (has1) {
        int t2 = tid;
        uint32_t a0, a1;
#if JAX_PARTITIONABLE
        tf_block(s_keys[4], s_keys[5], 0u, (uint32_t)t2, a0, a1);
        c1 = (a0 ^ a1) & 0xFFFFu;
#else
        if (t2 < 128) { tf_block(s_keys[4], s_keys[5], (uint32_t)t2, (uint32_t)(128 + t2), a0, a1);
                        c1 = a0 & 0xFFFFu; }
        else          { tf_block(s_keys[4], s_keys[5], (uint32_t)(t2 - 128), (uint32_t)t2, a0, a1);
                        c1 = a1 & 0xFFFFu; }
#endif
      }
    }
    s_cand[tid] = (unsigned short)c0;
    if (has1) s_cand[BLOCK_S + tid] = (unsigned short)c1;

    const float pi_i   = s_pi[step];
    const float i_pf   = (float)step;
    const float factor = (step > 0) ? (i_pf / fminf(i_pf, 32.0f)) : 0.0f;

    float un0, un1 = -3.402823466e+38f;
    {
      int w = __popc(c0);
      int m = 16 * w - 256 + step;
      float sq  = (float)(m * m) * 0.00390625f;
      float obk = (pi_i * sq) * 0.0625f;
      float s = 0.0f;
      for (int w2 = 0; w2 < WWIN; ++w2) {
        float ov = (float)(16 - __popc(c0 ^ (uint32_t)s_wc[w2]));
        s = s + s_pw[w2] * ov;
      }
      un0 = -(obk + factor * (pi_i * s));
    }
    if (has1) {
      int w = __popc(c1);
      int m = 16 * w - 256 + step;
      float sq  = (float)(m * m) * 0.00390625f;
      float obk = (pi_i * sq) * 0.0625f;
      float s = 0.0f;
      for (int w2 = 0; w2 < WWIN; ++w2) {
        float ov = (float)(16 - __popc(c1 ^ (uint32_t)s_wc[w2]));
        s = s + s_pw[w2] * ov;
      }
      un1 = -(obk + factor * (pi_i * s));
    }
    s_unnorm[tid] = un0;
    if (has1) s_unnorm[BLOCK_S + tid] = un1;

    float g0v = 0.0f, g1v = 0.0f;
    {
      const uint32_t ks0 = s_keys[2], ks1 = s_keys[3];
      g0v = gumbel_at(ks0, ks1, (uint32_t)(b * KC + tid));
      if (has1) g1v = gumbel_at(ks0, ks1, (uint32_t)(b * KC + BLOCK_S + tid));
    }

    float pmax = has1 ? fmaxf(un0, un1) : un0;
    for (int off = 32; off > 0; off >>= 1) pmax = fmaxf(pmax, __shfl_down(pmax, off));
    if ((tid & 63) == 0) s_redf[tid >> 6] = pmax;
    __syncthreads();
    if (tid == 0) {
      float mm = s_redf[0];
      for (int w2 = 1; w2 < NWAVE_S; ++w2) mm = fmaxf(mm, s_redf[w2]);
      s_bcast[0] = mm;
    }
    __syncthreads();
    const float rmax = s_bcast[0];

    double acc = (double)((float)exp((double)(un0 - rmax)));
    if (has1) acc += (double)((float)exp((double)(un1 - rmax)));
    for (int off = 32; off > 0; off >>= 1) acc += __shfl_down(acc, off);
    if ((tid & 63) == 0) s_redd[tid >> 6] = acc;
    __syncthreads();
    if (tid == 0) {
      double ss = 0.0;
      for (int w2 = 0; w2 < NWAVE_S; ++w2) ss += s_redd[w2];
      float sum_f = (float)ss;
      s_bcast[1] = (float)log((double)sum_f);
    }
    __syncthreads();
    const float lsum = s_bcast[1];

    float bz = ((un0 - rmax) - lsum) + g0v;
    int   bi = tid;
    if (has1) {
      float z1 = ((un1 - rmax) - lsum) + g1v;
      if (z1 > bz) { bz = z1; bi = BLOCK_S + tid; }
    }
    for (int off = 32; off > 0; off >>= 1) {
      float oz = __shfl_down(bz, off);
      int   oi = __shfl_down(bi, off);
      if (oz > bz || (oz == bz && oi < bi)) { bz = oz; bi = oi; }
    }
    if ((tid & 63) == 0) { s_redf[tid >> 6] = bz; s_redi[tid >> 6] = bi; }
    __syncthreads();
    if (tid == 0) {
      float bz2 = s_redf[0]; int bi2 = s_redi[0];
      for (int w2 = 1; w2 < NWAVE_S; ++w2) {
        if (s_redf[w2] > bz2 || (s_redf[w2] == bz2 && s_redi[w2] < bi2)) {
          bz2 = s_redf[w2]; bi2 = s_redi[w2];
        }
      }
      s_cint[step] = s_cand[bi2];
      float lpw = (s_unnorm[bi2] - rmax) - lsum;
      lp_acc += (double)lpw;
    }
    __syncthreads();
  }

  for (int idx2 = tid; idx2 < T_COLS * 32; idx2 += BLOCK_S) {
    int t    = idx2 >> 5;
    int rem  = idx2 & 31;
    int l    = rem >> 1;
    int sbit = rem & 1;
    uint32_t code = s_cint[t];
    int bit = (int)((code >> (15 - l)) & 1u);
    out[(size_t)b * 8192 + idx2] = (float)(sbit ? bit : (1 - bit));
  }
  if (tid == 0) {
    out[(size_t)B_ROWS * 8192 + b] = (float)(lp_acc / 256.0);
  }
}

extern "C" void kernel_launch(void* const* d_in, const int* in_sizes, int n_in,
                              void* d_out, int out_size, void* d_ws, size_t ws_size,
                              hipStream_t stream) {
  const float* pi = (const float*)d_in[0];
  float* out = (float*)d_out;

  const size_t cand_bytes = (size_t)T_COLS * KC * sizeof(unsigned short); // 655,360
  const size_t done_off   = cand_bytes;
  const size_t done_bytes = 1024;                                         // 128 ints (padded)
  const size_t gw2_off    = done_off + done_bytes;
  const size_t gw2_bytes  = (size_t)B_ROWS * HALF * KC * sizeof(float);   // 83,886,080

  if (ws_size >= gw2_off + gw2_bytes) {
    // hybrid path: [candg][done][gw2]
    unsigned short* candg = (unsigned short*)d_ws;
    int*   done = (int*)((char*)d_ws + done_off);
    float* gw2  = (float*)((char*)d_ws + gw2_off);
    hipMemsetAsync(done, 0, done_bytes, stream);
    cand_kernel<<<dim3(T_COLS), dim3(256), 0, stream>>>(candg);
    mrf_hybrid<<<dim3(2 * B_ROWS), dim3(NTHR), 0, stream>>>(
        pi, out, candg, gw2, done);
  } else if (ws_size >= cand_bytes) {
    // pure fused fallback (R27 behavior): gw2 = nullptr -> always compute
    unsigned short* candg = (unsigned short*)d_ws;
    cand_kernel<<<dim3(T_COLS), dim3(256), 0, stream>>>(candg);
    mrf_hybrid<<<dim3(B_ROWS), dim3(NTHR), 0, stream>>>(
        pi, out, candg, nullptr, nullptr);
  } else {
    mrf_seq_kernel<0><<<dim3(B_ROWS), dim3(BLOCK_S), 0, stream>>>(pi, out, nullptr, nullptr);
  }
}